// Round 2
// baseline (403.139 us; speedup 1.0000x reference)
//
#include <hip/hip_runtime.h>
#include <stdint.h>

typedef __bf16 bf16x8 __attribute__((ext_vector_type(8)));
typedef float f32x4 __attribute__((ext_vector_type(4)));
typedef unsigned short u16;
typedef unsigned int u32;

#define N_INST 50000
#define NPAD   50048   // 391 * 128
#define LIN    1024
#define D1     512
#define D2     256
#define TOPK   64
#define TDIM   49

__device__ __forceinline__ float b2f(u16 u) {
    union { float f; u32 i; } x; x.i = ((u32)u) << 16; return x.f;
}
__device__ __forceinline__ u16 f2b(float f) {
    union { float f; u32 i; } x; x.f = f;
    u32 r = x.i + 0x7FFFu + ((x.i >> 16) & 1u);   // RNE
    return (u16)(r >> 16);
}
// async global->LDS, 16B per lane. dst must be linear in lane order (wave-uniform base + lane*16).
__device__ __forceinline__ void gload16(const void* g, void* l) {
    __builtin_amdgcn_global_load_lds((const __attribute__((address_space(1))) void*)g,
                                     (__attribute__((address_space(3))) void*)l, 16, 0, 0);
}

// ---------------- pack: h fp32 -> bf16 [NPAD][1024] (zero pad rows); W_fc/Wa/Wb transposed bf16
__global__ void pack_all(const float* __restrict__ h, const float* __restrict__ W_fc,
                         const float* __restrict__ Wa, const float* __restrict__ Wb,
                         u16* __restrict__ hb, u16* __restrict__ WfcT,
                         u16* __restrict__ WaT, u16* __restrict__ WbT) {
    int gt = blockIdx.x * blockDim.x + threadIdx.x;
    int nthr = gridDim.x * blockDim.x;
    if (hb) {
        const int HC = NPAD * LIN / 8;          // 8 elems per chunk
        for (int c = gt; c < HC; c += nthr) {
            int row = c >> 7;                   // 128 chunks per row
            uint4 o;
            if (row < N_INST) {
                const float4* p = (const float4*)(h + (size_t)c * 8);
                float4 v0 = p[0], v1 = p[1];
                o.x = (u32)f2b(v0.x) | ((u32)f2b(v0.y) << 16);
                o.y = (u32)f2b(v0.z) | ((u32)f2b(v0.w) << 16);
                o.z = (u32)f2b(v1.x) | ((u32)f2b(v1.y) << 16);
                o.w = (u32)f2b(v1.z) | ((u32)f2b(v1.w) << 16);
            } else {
                o.x = o.y = o.z = o.w = 0u;
            }
            *(uint4*)(hb + (size_t)c * 8) = o;
        }
    }
    for (int e = gt; e < D1 * LIN; e += nthr) {
        int n = e >> 10, k = e & 1023;
        WfcT[e] = f2b(W_fc[(size_t)k * D1 + n]);
    }
    for (int f = gt; f < D2 * D1; f += nthr) {
        int j = f >> 9, k = f & 511;
        WaT[f] = f2b(Wa[(size_t)k * D2 + j]);
        WbT[f] = f2b(Wb[(size_t)k * D2 + j]);
    }
}

// ---------------- GEMM1 (fast path): h512 = relu(hb @ W_fc + b_fc). m97 structure:
// 128x128 tile, 4 waves (2x2), BK=64, global_load_lds(16B), linear LDS, ds_read_b128 frags.
__global__ __launch_bounds__(256, 3)
void gemm_fc_bf(const u16* __restrict__ hb, const u16* __restrict__ WfcT,
                const float* __restrict__ b_fc, u16* __restrict__ h512) {
    __shared__ __align__(16) u16 lA[128 * 64];
    __shared__ __align__(16) u16 lB[128 * 64];
    const int tid = threadIdx.x;
    const int lane = tid & 63, wid = tid >> 6;
    const int wr = wid >> 1, wc = wid & 1;          // 2x2 wave grid, 64x64 each
    const int lanelo = lane & 15, lanehi = lane >> 4;
    const int row0 = blockIdx.y * 128;
    const int col0 = blockIdx.x * 128;

    f32x4 acc[4][4];
    const f32x4 z4 = {0.f, 0.f, 0.f, 0.f};
    for (int m = 0; m < 4; ++m)
        for (int n = 0; n < 4; ++n) acc[m][n] = z4;

    for (int kt = 0; kt < LIN / 64; ++kt) {
        #pragma unroll
        for (int q = 0; q < 4; ++q) {               // A tile 128x64 bf16 = 1024 16B chunks
            int c = tid + 256 * q;
            int row = c >> 3, k8 = c & 7;
            gload16(hb + (size_t)(row0 + row) * LIN + kt * 64 + k8 * 8, (char*)lA + c * 16);
        }
        #pragma unroll
        for (int q = 0; q < 4; ++q) {               // B tile 128x64
            int c = tid + 256 * q;
            int col = c >> 3, k8 = c & 7;
            gload16(WfcT + (size_t)(col0 + col) * LIN + kt * 64 + k8 * 8, (char*)lB + c * 16);
        }
        __syncthreads();
        #pragma unroll
        for (int kk = 0; kk < 2; ++kk) {
            bf16x8 af[4], bfr[4];
            #pragma unroll
            for (int m = 0; m < 4; ++m)
                af[m] = *(const bf16x8*)((char*)lA + (wr * 64 + m * 16 + lanelo) * 128 + kk * 64 + lanehi * 16);
            #pragma unroll
            for (int n = 0; n < 4; ++n)
                bfr[n] = *(const bf16x8*)((char*)lB + (wc * 64 + n * 16 + lanelo) * 128 + kk * 64 + lanehi * 16);
            #pragma unroll
            for (int m = 0; m < 4; ++m)
                #pragma unroll
                for (int n = 0; n < 4; ++n)
                    acc[m][n] = __builtin_amdgcn_mfma_f32_16x16x32_bf16(af[m], bfr[n], acc[m][n], 0, 0, 0);
        }
        __syncthreads();
    }
    #pragma unroll
    for (int n = 0; n < 4; ++n) {
        int col = col0 + wc * 64 + n * 16 + lanelo;
        float bias = b_fc[col];
        #pragma unroll
        for (int m = 0; m < 4; ++m) {
            int rbase = row0 + wr * 64 + m * 16 + 4 * lanehi;
            #pragma unroll
            for (int r = 0; r < 4; ++r) {
                float v = acc[m][n][r] + bias;
                v = v > 0.f ? v : 0.f;
                h512[(size_t)(rbase + r) * D1 + col] = f2b(v);
            }
        }
    }
}

// ---------------- GEMM1 (fallback if workspace too small for hb): fp32 A, reg-staged
__global__ __launch_bounds__(512, 2)
void gemm_fc_f32(const float* __restrict__ h, const u16* __restrict__ WfcT,
                 const float* __restrict__ b_fc, u16* __restrict__ h512) {
    __shared__ __align__(16) u16 lA[128 * 64];
    __shared__ __align__(16) u16 lB[256 * 64];
    const int tid = threadIdx.x;
    const int lane = tid & 63, wid = tid >> 6;
    const int wr = wid >> 2, wc = wid & 3;
    const int lanelo = lane & 15, lanehi = lane >> 4;
    const int row0 = blockIdx.y * 128;
    const int col0 = blockIdx.x * 256;

    f32x4 acc[4][4];
    const f32x4 z4 = {0.f, 0.f, 0.f, 0.f};
    for (int m = 0; m < 4; ++m)
        for (int n = 0; n < 4; ++n) acc[m][n] = z4;

    for (int kt = 0; kt < LIN / 64; ++kt) {
        #pragma unroll
        for (int q = 0; q < 4; ++q) {
            int idx = tid + 512 * q;
            int row = idx >> 4, k4 = idx & 15;
            int srow = row0 + row; if (srow >= N_INST) srow = N_INST - 1;
            const float4 v = *(const float4*)(h + (size_t)srow * LIN + kt * 64 + k4 * 4);
            ushort4 b; b.x = f2b(v.x); b.y = f2b(v.y); b.z = f2b(v.z); b.w = f2b(v.w);
            u32 off = row * 128 + ((k4 * 8) ^ ((row & 7) << 4));
            *(ushort4*)((char*)lA + off) = b;
        }
        #pragma unroll
        for (int q = 0; q < 4; ++q) {
            int idx = tid + 512 * q;
            int c = idx >> 3, k8 = idx & 7;
            uint4 v = *(const uint4*)(WfcT + (size_t)(col0 + c) * LIN + kt * 64 + k8 * 8);
            u32 off = c * 128 + ((k8 * 16) ^ ((c & 7) << 4));
            *(uint4*)((char*)lB + off) = v;
        }
        __syncthreads();
        #pragma unroll
        for (int kk = 0; kk < 2; ++kk) {
            bf16x8 af[4], bfr[4];
            #pragma unroll
            for (int m = 0; m < 4; ++m) {
                int row = wr * 64 + m * 16 + lanelo;
                u32 off = row * 128 + (((u32)(kk * 64 + lanehi * 16)) ^ ((row & 7) << 4));
                af[m] = *(const bf16x8*)((char*)lA + off);
            }
            #pragma unroll
            for (int n = 0; n < 4; ++n) {
                int c = wc * 64 + n * 16 + lanelo;
                u32 off = c * 128 + (((u32)(kk * 64 + lanehi * 16)) ^ ((c & 7) << 4));
                bfr[n] = *(const bf16x8*)((char*)lB + off);
            }
            #pragma unroll
            for (int m = 0; m < 4; ++m)
                #pragma unroll
                for (int n = 0; n < 4; ++n)
                    acc[m][n] = __builtin_amdgcn_mfma_f32_16x16x32_bf16(af[m], bfr[n], acc[m][n], 0, 0, 0);
        }
        __syncthreads();
    }
    #pragma unroll
    for (int n = 0; n < 4; ++n) {
        int col = col0 + wc * 64 + n * 16 + lanelo;
        float bias = b_fc[col];
        #pragma unroll
        for (int m = 0; m < 4; ++m) {
            int rbase = row0 + wr * 64 + m * 16 + 4 * lanehi;
            #pragma unroll
            for (int r = 0; r < 4; ++r) {
                float v = acc[m][n][r] + bias;
                v = v > 0.f ? v : 0.f;
                h512[(size_t)(rbase + r) * D1 + col] = f2b(v);
            }
        }
    }
}

// ---------------- GEMM2 fused: a=tanh(h512@Wa+ba), b=sig(h512@Wb+bb), A_raw=(a*b)@Wc+bc
// + sortable keys, partial Z = sum exp(A_raw), partial M = sum exp(A_raw_i)*h512_i.
__global__ __launch_bounds__(512, 2)
void gemm_attn(const u16* __restrict__ h512, const u16* __restrict__ WaT,
               const u16* __restrict__ WbT, const float* __restrict__ ba,
               const float* __restrict__ bb, const float* __restrict__ Wc,
               const float* __restrict__ bc, float* __restrict__ araw,
               u32* __restrict__ uarr, float* __restrict__ Zacc, float* __restrict__ Mpart) {
    __shared__ __align__(16) u16 lA[128 * 64];
    __shared__ __align__(16) u16 lBa[256 * 64];
    __shared__ __align__(16) u16 lBb[256 * 64];
    __shared__ float rsum[128];
    __shared__ float sW[128];
    const int tid = threadIdx.x;
    const int lane = tid & 63, wid = tid >> 6;
    const int wr = wid >> 2, wc4 = wid & 3;
    const int lanelo = lane & 15, lanehi = lane >> 4;
    const int row0 = blockIdx.x * 128;

    f32x4 accA[4][4], accB[4][4];
    const f32x4 z4 = {0.f, 0.f, 0.f, 0.f};
    for (int m = 0; m < 4; ++m)
        for (int n = 0; n < 4; ++n) { accA[m][n] = z4; accB[m][n] = z4; }

    for (int kt = 0; kt < D1 / 64; ++kt) {
        #pragma unroll
        for (int q = 0; q < 2; ++q) {               // A: 128x64 bf16 = 1024 chunks
            int c = tid + 512 * q;
            int row = c >> 3, k8 = c & 7;
            gload16(h512 + (size_t)(row0 + row) * D1 + kt * 64 + k8 * 8, (char*)lA + c * 16);
        }
        #pragma unroll
        for (int q = 0; q < 4; ++q) {               // Ba/Bb: 256x64 each = 2048 chunks
            int c = tid + 512 * q;
            int col = c >> 3, k8 = c & 7;
            gload16(WaT + (size_t)col * D1 + kt * 64 + k8 * 8, (char*)lBa + c * 16);
            gload16(WbT + (size_t)col * D1 + kt * 64 + k8 * 8, (char*)lBb + c * 16);
        }
        __syncthreads();
        #pragma unroll
        for (int kk = 0; kk < 2; ++kk) {
            bf16x8 af[4], ga[4], gb[4];
            #pragma unroll
            for (int m = 0; m < 4; ++m)
                af[m] = *(const bf16x8*)((char*)lA + (wr * 64 + m * 16 + lanelo) * 128 + kk * 64 + lanehi * 16);
            #pragma unroll
            for (int n = 0; n < 4; ++n) {
                u32 off = (wc4 * 64 + n * 16 + lanelo) * 128 + kk * 64 + lanehi * 16;
                ga[n] = *(const bf16x8*)((char*)lBa + off);
                gb[n] = *(const bf16x8*)((char*)lBb + off);
            }
            #pragma unroll
            for (int m = 0; m < 4; ++m)
                #pragma unroll
                for (int n = 0; n < 4; ++n) {
                    accA[m][n] = __builtin_amdgcn_mfma_f32_16x16x32_bf16(af[m], ga[n], accA[m][n], 0, 0, 0);
                    accB[m][n] = __builtin_amdgcn_mfma_f32_16x16x32_bf16(af[m], gb[n], accB[m][n], 0, 0, 0);
                }
        }
        __syncthreads();
    }

    if (tid < 128) rsum[tid] = 0.f;
    __syncthreads();

    float baR[4], bbR[4], wcR[4];
    #pragma unroll
    for (int n = 0; n < 4; ++n) {
        int j = wc4 * 64 + n * 16 + lanelo;
        baR[n] = ba[j]; bbR[n] = bb[j]; wcR[n] = Wc[j];
    }
    #pragma unroll
    for (int m = 0; m < 4; ++m) {
        #pragma unroll
        for (int r = 0; r < 4; ++r) {
            float s = 0.f;
            #pragma unroll
            for (int n = 0; n < 4; ++n) {
                float av = accA[m][n][r] + baR[n];
                float bv = accB[m][n][r] + bbR[n];
                float p = tanhf(av) / (1.f + expf(-bv));
                s += p * wcR[n];
            }
            s += __shfl_xor(s, 1); s += __shfl_xor(s, 2);
            s += __shfl_xor(s, 4); s += __shfl_xor(s, 8);
            if (lanelo == 0) atomicAdd(&rsum[wr * 64 + m * 16 + 4 * lanehi + r], s);
        }
    }
    __syncthreads();

    if (tid < 128) {
        int rg = row0 + tid;
        float e = 0.f;
        if (rg < N_INST) {
            float a = rsum[tid] + bc[0];
            araw[rg] = a;
            u32 bits = __float_as_uint(a);
            uarr[rg] = (bits & 0x80000000u) ? ~bits : (bits | 0x80000000u);
            e = expf(a);                       // |a| small analytically: no max-sub needed
        }
        sW[tid] = e;
    }
    __syncthreads();
    if (tid < 128) {
        float e = sW[tid];
        for (int o = 32; o > 0; o >>= 1) e += __shfl_xor(e, o);
        if (lane == 0) atomicAdd(Zacc, e);
    }
    float accM = 0.f;
    for (int i = 0; i < 128; ++i)
        accM += sW[i] * b2f(h512[(size_t)(row0 + i) * D1 + tid]);
    atomicAdd(&Mpart[tid], accM);
}

// ---------------- radix top-64 / bottom-64 select (single block, 1024 threads)
__global__ void topk_sel(const u32* __restrict__ uarr, int* __restrict__ ids) {
    __shared__ u32 hist[256];
    __shared__ int tie[2048];
    __shared__ int s_digit, s_k, cnt, tcnt;
    const int tid = threadIdx.x;
    const int BD = 1024;

    for (int mode = 0; mode < 2; ++mode) {
        u32 prefix = 0; int k = TOPK;
        for (int shift = 24; shift >= 0; shift -= 8) {
            if (tid < 256) hist[tid] = 0;
            __syncthreads();
            u32 maskhi = (shift == 24) ? 0u : (0xFFFFFFFFu << (shift + 8));
            for (int i = tid; i < N_INST; i += BD) {
                u32 v = uarr[i];
                if ((v & maskhi) == prefix) atomicAdd(&hist[(v >> shift) & 255u], 1u);
            }
            __syncthreads();
            if (tid == 0) {
                int acc = 0, d;
                if (mode == 0) { for (d = 255; d >= 0; --d) { acc += (int)hist[d]; if (acc >= k) break; } }
                else           { for (d = 0; d <= 255; ++d) { acc += (int)hist[d]; if (acc >= k) break; } }
                s_digit = d; s_k = k - (acc - (int)hist[d]);
            }
            __syncthreads();
            prefix |= ((u32)s_digit) << shift;
            k = s_k;
            __syncthreads();
        }
        u32 vth = prefix;
        if (tid == 0) { cnt = 0; tcnt = 0; }
        __syncthreads();
        int* dst = ids + mode * TOPK;
        for (int i = tid; i < N_INST; i += BD) {
            u32 v = uarr[i];
            bool strict = mode == 0 ? (v > vth) : (v < vth);
            if (strict) { int p = atomicAdd(&cnt, 1); if (p < TOPK) dst[p] = i; }
            else if (v == vth) { int p = atomicAdd(&tcnt, 1); if (p < 2048) tie[p] = i; }
        }
        __syncthreads();
        if (tid == 0) {
            int have = cnt < TOPK ? cnt : TOPK;
            int need = TOPK - have;
            int m = tcnt < 2048 ? tcnt : 2048;
            int last = -1;
            for (int t = 0; t < need; ++t) {
                int best = 0x7FFFFFFF;
                for (int s = 0; s < m; ++s) { int ix = tie[s]; if (ix > last && ix < best) best = ix; }
                dst[have + t] = best; last = best;
            }
        }
        __syncthreads();
    }
}

// ---------------- instance CE loss over gathered 128 rows
__global__ void inst_loss(const u16* __restrict__ h512, const int* __restrict__ ids,
                          const float* __restrict__ W_inst, const float* __restrict__ b_inst,
                          const int* __restrict__ label, float* __restrict__ out_loss) {
    __shared__ float lsum;
    const int tid = threadIdx.x;               // 256
    const int lane = tid & 63, wid = tid >> 6;
    if (tid == 0) lsum = 0.f;
    __syncthreads();
    const int lab = label[0];
    const float* W = W_inst + (size_t)lab * (D1 * 2);
    const float b0 = b_inst[lab * 2 + 0], b1 = b_inst[lab * 2 + 1];
    for (int i = 0; i < 32; ++i) {
        int r = wid * 32 + i;
        int row = ids[r];
        float s0 = 0.f, s1 = 0.f;
        for (int s = 0; s < 8; ++s) {
            int j = lane + 64 * s;
            float hv = b2f(h512[(size_t)row * D1 + j]);
            s0 += hv * W[j * 2 + 0];
            s1 += hv * W[j * 2 + 1];
        }
        for (int o = 32; o > 0; o >>= 1) { s0 += __shfl_xor(s0, o); s1 += __shfl_xor(s1, o); }
        if (lane == 0) {
            float l0 = s0 + b0, l1 = s1 + b1;
            float mx = fmaxf(l0, l1);
            float lse = mx + logf(expf(l0 - mx) + expf(l1 - mx));
            float lt = (r < TOPK) ? l1 : l0;
            atomicAdd(&lsum, lse - lt);
        }
    }
    __syncthreads();
    if (tid == 0) out_loss[0] = lsum / 128.f;
}

// ---------------- final head
__global__ void final_head(const float* __restrict__ Mpart, const float* __restrict__ Zacc,
                           const float* __restrict__ tabular, const float* __restrict__ W_img,
                           const float* __restrict__ b_img, const float* __restrict__ W_tab,
                           const float* __restrict__ b_tab, const float* __restrict__ W_cls,
                           const float* __restrict__ b_cls, float* __restrict__ d_out) {
    __shared__ float sM[512];
    __shared__ float stab[TDIM];
    __shared__ float red0[256], red1[256];
    __shared__ float simg;
    const int tid = threadIdx.x;               // 256
    float invZ = 1.f / Zacc[0];
    sM[tid] = Mpart[tid] * invZ;
    sM[tid + 256] = Mpart[tid + 256] * invZ;
    red0[tid] = sM[tid] * W_img[tid] + sM[tid + 256] * W_img[tid + 256];
    __syncthreads();
    for (int o = 128; o > 0; o >>= 1) { if (tid < o) red0[tid] += red0[tid + o]; __syncthreads(); }
    if (tid == 0) simg = 1.f / (1.f + expf(-(red0[0] + b_img[0])));
    if (tid < TDIM) {
        float t = b_tab[tid];
        for (int kx = 0; kx < TDIM; ++kx) t += tabular[kx] * W_tab[kx * TDIM + tid];
        stab[tid] = t;
    }
    __syncthreads();
    if (tid == 0) {
        float mx = stab[0];
        for (int o = 1; o < TDIM; ++o) mx = fmaxf(mx, stab[o]);
        float ss = 0.f;
        for (int o = 0; o < TDIM; ++o) { float e = expf(stab[o] - mx); stab[o] = e; ss += e; }
        for (int o = 0; o < TDIM; ++o) stab[o] = (stab[o] / ss) * tabular[o];
    }
    __syncthreads();
    float img = simg;
    float a0 = 0.f, a1 = 0.f;
    for (int j = tid; j < D1 + TDIM; j += 256) {
        float w = (j < D1) ? img * sM[j] : stab[j - D1];
        a0 += w * W_cls[j * 2 + 0];
        a1 += w * W_cls[j * 2 + 1];
    }
    red0[tid] = a0; red1[tid] = a1;
    __syncthreads();
    for (int o = 128; o > 0; o >>= 1) {
        if (tid < o) { red0[tid] += red0[tid + o]; red1[tid] += red1[tid + o]; }
        __syncthreads();
    }
    if (tid == 0) {
        float l0 = red0[0] + b_cls[0];
        float l1 = red1[0] + b_cls[1];
        d_out[0] = l0; d_out[1] = l1;
        float mx = fmaxf(l0, l1);
        float e0 = expf(l0 - mx), e1 = expf(l1 - mx);
        d_out[2] = e0 / (e0 + e1);
        d_out[3] = e1 / (e0 + e1);
        d_out[4] = (l1 > l0) ? 1.f : 0.f;
    }
}

extern "C" void kernel_launch(void* const* d_in, const int* in_sizes, int n_in,
                              void* d_out, int out_size, void* d_ws, size_t ws_size,
                              hipStream_t stream) {
    const float* h       = (const float*)d_in[0];
    const float* tabular = (const float*)d_in[1];
    const int*   label   = (const int*)d_in[2];
    const float* W_fc    = (const float*)d_in[3];
    const float* b_fc    = (const float*)d_in[4];
    const float* Wa      = (const float*)d_in[5];
    const float* ba      = (const float*)d_in[6];
    const float* Wb      = (const float*)d_in[7];
    const float* bb      = (const float*)d_in[8];
    const float* Wc      = (const float*)d_in[9];
    const float* bc      = (const float*)d_in[10];
    const float* W_inst  = (const float*)d_in[11];
    const float* b_inst  = (const float*)d_in[12];
    const float* W_img   = (const float*)d_in[13];
    const float* b_img   = (const float*)d_in[14];
    const float* W_tab   = (const float*)d_in[15];
    const float* b_tab   = (const float*)d_in[16];
    const float* W_cls   = (const float*)d_in[17];
    const float* b_cls   = (const float*)d_in[18];
    float* out = (float*)d_out;

    // workspace layout (hb last so small-ws fallback works)
    u16* h512 = (u16*)d_ws;                          // NPAD x 512 bf16      (51.2 MB)
    u16* WfcT = h512 + (size_t)NPAD * D1;            // 512 x 1024 bf16      (1 MB)
    u16* WaT  = WfcT + (size_t)D1 * LIN;             // 256 x 512 bf16
    u16* WbT  = WaT + (size_t)D2 * D1;
    u32* uarr = (u32*)(WbT + (size_t)D2 * D1);       // NPAD sortable keys
    float* accum = (float*)(uarr + NPAD);            // [0]=Z, [8..520)=Mpart
    float* Zacc  = accum;
    float* Mpart = accum + 8;
    int* ids = (int*)(accum + 8 + D1);               // 128 selected indices
    u16* hb = (u16*)(ids + 128);                     // NPAD x 1024 bf16     (102.5 MB)
    size_t need = ((char*)(hb + (size_t)NPAD * LIN)) - (char*)d_ws;
    bool fast = ws_size >= need;

    hipMemsetAsync(accum, 0, (8 + D1) * sizeof(float), stream);
    pack_all<<<dim3(1024), dim3(256), 0, stream>>>(h, W_fc, Wa, Wb,
                                                   fast ? hb : (u16*)nullptr, WfcT, WaT, WbT);
    if (fast) {
        gemm_fc_bf<<<dim3(4, NPAD / 128), dim3(256), 0, stream>>>(hb, WfcT, b_fc, h512);
    } else {
        gemm_fc_f32<<<dim3(2, NPAD / 128), dim3(512), 0, stream>>>(h, WfcT, b_fc, h512);
    }
    gemm_attn<<<dim3(NPAD / 128), dim3(512), 0, stream>>>(
        h512, WaT, WbT, ba, bb, Wc, bc, out + 5, uarr, Zacc, Mpart);
    topk_sel<<<dim3(1), dim3(1024), 0, stream>>>(uarr, ids);
    inst_loss<<<dim3(1), dim3(256), 0, stream>>>(h512, ids, W_inst, b_inst, label, out + 50005);
    final_head<<<dim3(1), dim3(256), 0, stream>>>(
        Mpart, Zacc, tabular, W_img, b_img, W_tab, b_tab, W_cls, b_cls, out);
}

// Round 3
// 347.883 us; speedup vs baseline: 1.1588x; 1.1588x over previous
//
#include <hip/hip_runtime.h>
#include <stdint.h>

typedef __bf16 bf16x8 __attribute__((ext_vector_type(8)));
typedef float f32x4 __attribute__((ext_vector_type(4)));
typedef unsigned short u16;
typedef unsigned int u32;

#define N_INST 50000
#define NPAD   50048   // 391 * 128
#define LIN    1024
#define D1     512
#define D2     256
#define TOPK   64
#define TDIM   49
#define NBIN   65536
#define CAND_MAX 8192

__device__ __forceinline__ float b2f(u16 u) {
    union { float f; u32 i; } x; x.i = ((u32)u) << 16; return x.f;
}
__device__ __forceinline__ u16 f2b(float f) {
    union { float f; u32 i; } x; x.f = f;
    u32 r = x.i + 0x7FFFu + ((x.i >> 16) & 1u);   // RNE
    return (u16)(r >> 16);
}
// async global->LDS, 16B per lane. dst must be linear in lane order (wave-uniform base + lane*16).
__device__ __forceinline__ void gload16(const void* g, void* l) {
    __builtin_amdgcn_global_load_lds((const __attribute__((address_space(1))) void*)g,
                                     (__attribute__((address_space(3))) void*)l, 16, 0, 0);
}

// ---------------- pack: h fp32 -> bf16 [NPAD][1024] (zero pad rows); W_fc/Wa/Wb transposed bf16
__global__ void pack_all(const float* __restrict__ h, const float* __restrict__ W_fc,
                         const float* __restrict__ Wa, const float* __restrict__ Wb,
                         u16* __restrict__ hb, u16* __restrict__ WfcT,
                         u16* __restrict__ WaT, u16* __restrict__ WbT) {
    int gt = blockIdx.x * blockDim.x + threadIdx.x;
    int nthr = gridDim.x * blockDim.x;
    if (hb) {
        const int HC = NPAD * LIN / 8;          // 8 elems per chunk
        for (int c = gt; c < HC; c += nthr) {
            int row = c >> 7;                   // 128 chunks per row
            uint4 o;
            if (row < N_INST) {
                const float4* p = (const float4*)(h + (size_t)c * 8);
                float4 v0 = p[0], v1 = p[1];
                o.x = (u32)f2b(v0.x) | ((u32)f2b(v0.y) << 16);
                o.y = (u32)f2b(v0.z) | ((u32)f2b(v0.w) << 16);
                o.z = (u32)f2b(v1.x) | ((u32)f2b(v1.y) << 16);
                o.w = (u32)f2b(v1.z) | ((u32)f2b(v1.w) << 16);
            } else {
                o.x = o.y = o.z = o.w = 0u;
            }
            *(uint4*)(hb + (size_t)c * 8) = o;
        }
    }
    for (int e = gt; e < D1 * LIN; e += nthr) {
        int n = e >> 10, k = e & 1023;
        WfcT[e] = f2b(W_fc[(size_t)k * D1 + n]);
    }
    for (int f = gt; f < D2 * D1; f += nthr) {
        int j = f >> 9, k = f & 511;
        WaT[f] = f2b(Wa[(size_t)k * D2 + j]);
        WbT[f] = f2b(Wb[(size_t)k * D2 + j]);
    }
}

// ---------------- GEMM1 (fast path): h512 = relu(hb @ W_fc + b_fc). m97 structure.
__global__ __launch_bounds__(256, 3)
void gemm_fc_bf(const u16* __restrict__ hb, const u16* __restrict__ WfcT,
                const float* __restrict__ b_fc, u16* __restrict__ h512) {
    __shared__ __align__(16) u16 lA[128 * 64];
    __shared__ __align__(16) u16 lB[128 * 64];
    const int tid = threadIdx.x;
    const int lane = tid & 63, wid = tid >> 6;
    const int wr = wid >> 1, wc = wid & 1;
    const int lanelo = lane & 15, lanehi = lane >> 4;
    const int row0 = blockIdx.y * 128;
    const int col0 = blockIdx.x * 128;

    f32x4 acc[4][4];
    const f32x4 z4 = {0.f, 0.f, 0.f, 0.f};
    for (int m = 0; m < 4; ++m)
        for (int n = 0; n < 4; ++n) acc[m][n] = z4;

    for (int kt = 0; kt < LIN / 64; ++kt) {
        #pragma unroll
        for (int q = 0; q < 4; ++q) {
            int c = tid + 256 * q;
            int row = c >> 3, k8 = c & 7;
            gload16(hb + (size_t)(row0 + row) * LIN + kt * 64 + k8 * 8, (char*)lA + c * 16);
        }
        #pragma unroll
        for (int q = 0; q < 4; ++q) {
            int c = tid + 256 * q;
            int col = c >> 3, k8 = c & 7;
            gload16(WfcT + (size_t)(col0 + col) * LIN + kt * 64 + k8 * 8, (char*)lB + c * 16);
        }
        __syncthreads();
        #pragma unroll
        for (int kk = 0; kk < 2; ++kk) {
            bf16x8 af[4], bfr[4];
            #pragma unroll
            for (int m = 0; m < 4; ++m)
                af[m] = *(const bf16x8*)((char*)lA + (wr * 64 + m * 16 + lanelo) * 128 + kk * 64 + lanehi * 16);
            #pragma unroll
            for (int n = 0; n < 4; ++n)
                bfr[n] = *(const bf16x8*)((char*)lB + (wc * 64 + n * 16 + lanelo) * 128 + kk * 64 + lanehi * 16);
            #pragma unroll
            for (int m = 0; m < 4; ++m)
                #pragma unroll
                for (int n = 0; n < 4; ++n)
                    acc[m][n] = __builtin_amdgcn_mfma_f32_16x16x32_bf16(af[m], bfr[n], acc[m][n], 0, 0, 0);
        }
        __syncthreads();
    }
    #pragma unroll
    for (int n = 0; n < 4; ++n) {
        int col = col0 + wc * 64 + n * 16 + lanelo;
        float bias = b_fc[col];
        #pragma unroll
        for (int m = 0; m < 4; ++m) {
            int rbase = row0 + wr * 64 + m * 16 + 4 * lanehi;
            #pragma unroll
            for (int r = 0; r < 4; ++r) {
                float v = acc[m][n][r] + bias;
                v = v > 0.f ? v : 0.f;
                h512[(size_t)(rbase + r) * D1 + col] = f2b(v);
            }
        }
    }
}

// ---------------- GEMM1 (fallback if workspace too small for hb): fp32 A, reg-staged
__global__ __launch_bounds__(512, 2)
void gemm_fc_f32(const float* __restrict__ h, const u16* __restrict__ WfcT,
                 const float* __restrict__ b_fc, u16* __restrict__ h512) {
    __shared__ __align__(16) u16 lA[128 * 64];
    __shared__ __align__(16) u16 lB[256 * 64];
    const int tid = threadIdx.x;
    const int lane = tid & 63, wid = tid >> 6;
    const int wr = wid >> 2, wc = wid & 3;
    const int lanelo = lane & 15, lanehi = lane >> 4;
    const int row0 = blockIdx.y * 128;
    const int col0 = blockIdx.x * 256;

    f32x4 acc[4][4];
    const f32x4 z4 = {0.f, 0.f, 0.f, 0.f};
    for (int m = 0; m < 4; ++m)
        for (int n = 0; n < 4; ++n) acc[m][n] = z4;

    for (int kt = 0; kt < LIN / 64; ++kt) {
        #pragma unroll
        for (int q = 0; q < 4; ++q) {
            int idx = tid + 512 * q;
            int row = idx >> 4, k4 = idx & 15;
            int srow = row0 + row; if (srow >= N_INST) srow = N_INST - 1;
            const float4 v = *(const float4*)(h + (size_t)srow * LIN + kt * 64 + k4 * 4);
            ushort4 b; b.x = f2b(v.x); b.y = f2b(v.y); b.z = f2b(v.z); b.w = f2b(v.w);
            u32 off = row * 128 + ((k4 * 8) ^ ((row & 7) << 4));
            *(ushort4*)((char*)lA + off) = b;
        }
        #pragma unroll
        for (int q = 0; q < 4; ++q) {
            int idx = tid + 512 * q;
            int c = idx >> 3, k8 = idx & 7;
            uint4 v = *(const uint4*)(WfcT + (size_t)(col0 + c) * LIN + kt * 64 + k8 * 8);
            u32 off = c * 128 + ((k8 * 16) ^ ((c & 7) << 4));
            *(uint4*)((char*)lB + off) = v;
        }
        __syncthreads();
        #pragma unroll
        for (int kk = 0; kk < 2; ++kk) {
            bf16x8 af[4], bfr[4];
            #pragma unroll
            for (int m = 0; m < 4; ++m) {
                int row = wr * 64 + m * 16 + lanelo;
                u32 off = row * 128 + (((u32)(kk * 64 + lanehi * 16)) ^ ((row & 7) << 4));
                af[m] = *(const bf16x8*)((char*)lA + off);
            }
            #pragma unroll
            for (int n = 0; n < 4; ++n) {
                int c = wc * 64 + n * 16 + lanelo;
                u32 off = c * 128 + (((u32)(kk * 64 + lanehi * 16)) ^ ((c & 7) << 4));
                bfr[n] = *(const bf16x8*)((char*)lB + off);
            }
            #pragma unroll
            for (int m = 0; m < 4; ++m)
                #pragma unroll
                for (int n = 0; n < 4; ++n)
                    acc[m][n] = __builtin_amdgcn_mfma_f32_16x16x32_bf16(af[m], bfr[n], acc[m][n], 0, 0, 0);
        }
        __syncthreads();
    }
    #pragma unroll
    for (int n = 0; n < 4; ++n) {
        int col = col0 + wc * 64 + n * 16 + lanelo;
        float bias = b_fc[col];
        #pragma unroll
        for (int m = 0; m < 4; ++m) {
            int rbase = row0 + wr * 64 + m * 16 + 4 * lanehi;
            #pragma unroll
            for (int r = 0; r < 4; ++r) {
                float v = acc[m][n][r] + bias;
                v = v > 0.f ? v : 0.f;
                h512[(size_t)(rbase + r) * D1 + col] = f2b(v);
            }
        }
    }
}

// ---------------- GEMM2 fused + sortable keys + 64K-bin key histogram + Z/M partials
__global__ __launch_bounds__(512, 2)
void gemm_attn(const u16* __restrict__ h512, const u16* __restrict__ WaT,
               const u16* __restrict__ WbT, const float* __restrict__ ba,
               const float* __restrict__ bb, const float* __restrict__ Wc,
               const float* __restrict__ bc, float* __restrict__ araw,
               u32* __restrict__ uarr, u32* __restrict__ hist,
               float* __restrict__ Zacc, float* __restrict__ Mpart) {
    __shared__ __align__(16) u16 lA[128 * 64];
    __shared__ __align__(16) u16 lBa[256 * 64];
    __shared__ __align__(16) u16 lBb[256 * 64];
    __shared__ float rsum[128];
    __shared__ float sW[128];
    const int tid = threadIdx.x;
    const int lane = tid & 63, wid = tid >> 6;
    const int wr = wid >> 2, wc4 = wid & 3;
    const int lanelo = lane & 15, lanehi = lane >> 4;
    const int row0 = blockIdx.x * 128;

    f32x4 accA[4][4], accB[4][4];
    const f32x4 z4 = {0.f, 0.f, 0.f, 0.f};
    for (int m = 0; m < 4; ++m)
        for (int n = 0; n < 4; ++n) { accA[m][n] = z4; accB[m][n] = z4; }

    for (int kt = 0; kt < D1 / 64; ++kt) {
        #pragma unroll
        for (int q = 0; q < 2; ++q) {
            int c = tid + 512 * q;
            int row = c >> 3, k8 = c & 7;
            gload16(h512 + (size_t)(row0 + row) * D1 + kt * 64 + k8 * 8, (char*)lA + c * 16);
        }
        #pragma unroll
        for (int q = 0; q < 4; ++q) {
            int c = tid + 512 * q;
            int col = c >> 3, k8 = c & 7;
            gload16(WaT + (size_t)col * D1 + kt * 64 + k8 * 8, (char*)lBa + c * 16);
            gload16(WbT + (size_t)col * D1 + kt * 64 + k8 * 8, (char*)lBb + c * 16);
        }
        __syncthreads();
        #pragma unroll
        for (int kk = 0; kk < 2; ++kk) {
            bf16x8 af[4], ga[4], gb[4];
            #pragma unroll
            for (int m = 0; m < 4; ++m)
                af[m] = *(const bf16x8*)((char*)lA + (wr * 64 + m * 16 + lanelo) * 128 + kk * 64 + lanehi * 16);
            #pragma unroll
            for (int n = 0; n < 4; ++n) {
                u32 off = (wc4 * 64 + n * 16 + lanelo) * 128 + kk * 64 + lanehi * 16;
                ga[n] = *(const bf16x8*)((char*)lBa + off);
                gb[n] = *(const bf16x8*)((char*)lBb + off);
            }
            #pragma unroll
            for (int m = 0; m < 4; ++m)
                #pragma unroll
                for (int n = 0; n < 4; ++n) {
                    accA[m][n] = __builtin_amdgcn_mfma_f32_16x16x32_bf16(af[m], ga[n], accA[m][n], 0, 0, 0);
                    accB[m][n] = __builtin_amdgcn_mfma_f32_16x16x32_bf16(af[m], gb[n], accB[m][n], 0, 0, 0);
                }
        }
        __syncthreads();
    }

    if (tid < 128) rsum[tid] = 0.f;
    __syncthreads();

    float baR[4], bbR[4], wcR[4];
    #pragma unroll
    for (int n = 0; n < 4; ++n) {
        int j = wc4 * 64 + n * 16 + lanelo;
        baR[n] = ba[j]; bbR[n] = bb[j]; wcR[n] = Wc[j];
    }
    #pragma unroll
    for (int m = 0; m < 4; ++m) {
        #pragma unroll
        for (int r = 0; r < 4; ++r) {
            float s = 0.f;
            #pragma unroll
            for (int n = 0; n < 4; ++n) {
                float av = accA[m][n][r] + baR[n];
                float bv = accB[m][n][r] + bbR[n];
                float p = tanhf(av) / (1.f + expf(-bv));
                s += p * wcR[n];
            }
            s += __shfl_xor(s, 1); s += __shfl_xor(s, 2);
            s += __shfl_xor(s, 4); s += __shfl_xor(s, 8);
            if (lanelo == 0) atomicAdd(&rsum[wr * 64 + m * 16 + 4 * lanehi + r], s);
        }
    }
    __syncthreads();

    if (tid < 128) {
        int rg = row0 + tid;
        float e = 0.f;
        if (rg < N_INST) {
            float a = rsum[tid] + bc[0];
            araw[rg] = a;
            u32 bits = __float_as_uint(a);
            u32 key = (bits & 0x80000000u) ? ~bits : (bits | 0x80000000u);
            uarr[rg] = key;
            atomicAdd(&hist[key >> 16], 1u);
            e = expf(a);
        }
        sW[tid] = e;
    }
    __syncthreads();
    if (tid < 128) {
        float e = sW[tid];
        for (int o = 32; o > 0; o >>= 1) e += __shfl_xor(e, o);
        if (lane == 0) atomicAdd(Zacc, e);
    }
    float accM = 0.f;
    for (int i = 0; i < 128; ++i)
        accM += sW[i] * b2f(h512[(size_t)(row0 + i) * D1 + tid]);
    atomicAdd(&Mpart[tid], accM);
}

// ---------------- topk phase 1: scan 64K-bin histogram, find boundary buckets
// ctl: [0]=p0 [1]=base0 [2]=p1 [3]=base1; [8..11] = counters (zeroed by memset)
__global__ void topk_scan(const u32* __restrict__ hist, int* __restrict__ ctl) {
    __shared__ int lds[1024];
    const int tid = threadIdx.x;               // 1024
    const int base = tid * 64;
    int local = 0;
    for (int i = 0; i < 64; ++i) local += (int)hist[base + i];
    lds[tid] = local;
    __syncthreads();
    for (int off = 1; off < 1024; off <<= 1) {
        int v = lds[tid];
        int add = (tid >= off) ? lds[tid - off] : 0;
        __syncthreads();
        lds[tid] = v + add;
        __syncthreads();
    }
    int run = lds[tid] - local;                // exclusive prefix = S(base)
    for (int i = 0; i < 64; ++i) {
        int b = base + i;
        int cnt = (int)hist[b];
        if (cnt > 0) {
            int less = run;
            int greater = N_INST - run - cnt;
            if (greater < TOPK && greater + cnt >= TOPK) { ctl[0] = b; ctl[1] = greater; }
            if (less < TOPK && less + cnt >= TOPK)       { ctl[2] = b; ctl[3] = less; }
        }
        run += cnt;
    }
}

// ---------------- topk phase 2: one pass — directs into ids, boundary-bucket candidates out
__global__ void topk_collect(const u32* __restrict__ uarr, int* __restrict__ ctl,
                             int* __restrict__ ids, u32* __restrict__ cV0, int* __restrict__ cI0,
                             u32* __restrict__ cV1, int* __restrict__ cI1) {
    const int p0 = ctl[0], p1 = ctl[2];
    int gt = blockIdx.x * blockDim.x + threadIdx.x;
    int nthr = gridDim.x * blockDim.x;
    for (int i = gt; i < N_INST; i += nthr) {
        u32 v = uarr[i];
        int b = (int)(v >> 16);
        if (b > p0)       { int p = atomicAdd(&ctl[8], 1);  ids[p] = i; }
        else if (b == p0) { int p = atomicAdd(&ctl[9], 1);  if (p < CAND_MAX) { cV0[p] = v; cI0[p] = i; } }
        if (b < p1)       { int p = atomicAdd(&ctl[10], 1); ids[TOPK + p] = i; }
        else if (b == p1) { int p = atomicAdd(&ctl[11], 1); if (p < CAND_MAX) { cV1[p] = v; cI1[p] = i; } }
    }
}

// ---------------- topk phase 3: finish selection within boundary bucket (tiny)
__global__ void topk_finish(const int* __restrict__ ctl,
                            const u32* __restrict__ cV0, const int* __restrict__ cI0,
                            const u32* __restrict__ cV1, const int* __restrict__ cI1,
                            int* __restrict__ ids) {
    __shared__ int h8[256];
    __shared__ int eq[2048];
    __shared__ int s_d1, s_k1, s_d2, s_fill, s_eqc;
    const int tid = threadIdx.x;               // 256
    for (int mode = 0; mode < 2; ++mode) {
        int basem = ctl[mode * 2 + 1];
        int need = TOPK - basem;
        int ccnt = ctl[9 + mode * 2];
        if (ccnt > CAND_MAX) ccnt = CAND_MAX;
        const u32* cV = mode ? cV1 : cV0;
        const int* cI = mode ? cI1 : cI0;
        int* dst = ids + mode * TOPK;
        // level 1: bits 15:8
        h8[tid] = 0; __syncthreads();
        for (int i = tid; i < ccnt; i += 256) atomicAdd(&h8[(cV[i] >> 8) & 255u], 1);
        __syncthreads();
        if (tid == 0) {
            int acc = 0, d, k = need;
            if (mode == 0) { for (d = 255; d >= 0; --d) { acc += h8[d]; if (acc >= k) break; } }
            else           { for (d = 0; d < 256; ++d)  { acc += h8[d]; if (acc >= k) break; } }
            s_d1 = d; s_k1 = k - (acc - h8[d]);
        }
        __syncthreads();
        int d1 = s_d1, k1 = s_k1;
        // level 2: bits 7:0 among digit-d1 candidates
        h8[tid] = 0; __syncthreads();
        for (int i = tid; i < ccnt; i += 256) {
            u32 v = cV[i];
            if (((v >> 8) & 255u) == (u32)d1) atomicAdd(&h8[v & 255u], 1);
        }
        __syncthreads();
        if (tid == 0) {
            int acc = 0, d, k = k1;
            if (mode == 0) { for (d = 255; d >= 0; --d) { acc += h8[d]; if (acc >= k) break; } }
            else           { for (d = 0; d < 256; ++d)  { acc += h8[d]; if (acc >= k) break; } }
            s_d2 = d; s_fill = 0; s_eqc = 0;
        }
        __syncthreads();
        u32 vth = ((u32)ctl[mode * 2] << 16) | ((u32)d1 << 8) | (u32)s_d2;
        for (int i = tid; i < ccnt; i += 256) {
            u32 v = cV[i];
            bool better = mode == 0 ? (v > vth) : (v < vth);
            if (better)        { int p = atomicAdd(&s_fill, 1); dst[basem + p] = cI[i]; }
            else if (v == vth) { int p = atomicAdd(&s_eqc, 1);  if (p < 2048) eq[p] = cI[i]; }
        }
        __syncthreads();
        if (tid == 0) {
            int have = basem + s_fill;
            int rem = TOPK - have;
            int m = s_eqc < 2048 ? s_eqc : 2048;
            int last = -1;
            for (int t = 0; t < rem; ++t) {
                int best = 0x7FFFFFFF;
                for (int s = 0; s < m; ++s) { int ix = eq[s]; if (ix > last && ix < best) best = ix; }
                dst[have + t] = best; last = best;
            }
        }
        __syncthreads();
    }
}

// ---------------- instance CE loss over gathered 128 rows
__global__ void inst_loss(const u16* __restrict__ h512, const int* __restrict__ ids,
                          const float* __restrict__ W_inst, const float* __restrict__ b_inst,
                          const int* __restrict__ label, float* __restrict__ out_loss) {
    __shared__ float lsum;
    const int tid = threadIdx.x;               // 256
    const int lane = tid & 63, wid = tid >> 6;
    if (tid == 0) lsum = 0.f;
    __syncthreads();
    const int lab = label[0];
    const float* W = W_inst + (size_t)lab * (D1 * 2);
    const float b0 = b_inst[lab * 2 + 0], b1 = b_inst[lab * 2 + 1];
    for (int i = 0; i < 32; ++i) {
        int r = wid * 32 + i;
        int row = ids[r];
        float s0 = 0.f, s1 = 0.f;
        for (int s = 0; s < 8; ++s) {
            int j = lane + 64 * s;
            float hv = b2f(h512[(size_t)row * D1 + j]);
            s0 += hv * W[j * 2 + 0];
            s1 += hv * W[j * 2 + 1];
        }
        for (int o = 32; o > 0; o >>= 1) { s0 += __shfl_xor(s0, o); s1 += __shfl_xor(s1, o); }
        if (lane == 0) {
            float l0 = s0 + b0, l1 = s1 + b1;
            float mx = fmaxf(l0, l1);
            float lse = mx + logf(expf(l0 - mx) + expf(l1 - mx));
            float lt = (r < TOPK) ? l1 : l0;
            atomicAdd(&lsum, lse - lt);
        }
    }
    __syncthreads();
    if (tid == 0) out_loss[0] = lsum / 128.f;
}

// ---------------- final head
__global__ void final_head(const float* __restrict__ Mpart, const float* __restrict__ Zacc,
                           const float* __restrict__ tabular, const float* __restrict__ W_img,
                           const float* __restrict__ b_img, const float* __restrict__ W_tab,
                           const float* __restrict__ b_tab, const float* __restrict__ W_cls,
                           const float* __restrict__ b_cls, float* __restrict__ d_out) {
    __shared__ float sM[512];
    __shared__ float stab[TDIM];
    __shared__ float red0[256], red1[256];
    __shared__ float simg;
    const int tid = threadIdx.x;               // 256
    float invZ = 1.f / Zacc[0];
    sM[tid] = Mpart[tid] * invZ;
    sM[tid + 256] = Mpart[tid + 256] * invZ;
    red0[tid] = sM[tid] * W_img[tid] + sM[tid + 256] * W_img[tid + 256];
    __syncthreads();
    for (int o = 128; o > 0; o >>= 1) { if (tid < o) red0[tid] += red0[tid + o]; __syncthreads(); }
    if (tid == 0) simg = 1.f / (1.f + expf(-(red0[0] + b_img[0])));
    if (tid < TDIM) {
        float t = b_tab[tid];
        for (int kx = 0; kx < TDIM; ++kx) t += tabular[kx] * W_tab[kx * TDIM + tid];
        stab[tid] = t;
    }
    __syncthreads();
    if (tid == 0) {
        float mx = stab[0];
        for (int o = 1; o < TDIM; ++o) mx = fmaxf(mx, stab[o]);
        float ss = 0.f;
        for (int o = 0; o < TDIM; ++o) { float e = expf(stab[o] - mx); stab[o] = e; ss += e; }
        for (int o = 0; o < TDIM; ++o) stab[o] = (stab[o] / ss) * tabular[o];
    }
    __syncthreads();
    float img = simg;
    float a0 = 0.f, a1 = 0.f;
    for (int j = tid; j < D1 + TDIM; j += 256) {
        float w = (j < D1) ? img * sM[j] : stab[j - D1];
        a0 += w * W_cls[j * 2 + 0];
        a1 += w * W_cls[j * 2 + 1];
    }
    red0[tid] = a0; red1[tid] = a1;
    __syncthreads();
    for (int o = 128; o > 0; o >>= 1) {
        if (tid < o) { red0[tid] += red0[tid + o]; red1[tid] += red1[tid + o]; }
        __syncthreads();
    }
    if (tid == 0) {
        float l0 = red0[0] + b_cls[0];
        float l1 = red1[0] + b_cls[1];
        d_out[0] = l0; d_out[1] = l1;
        float mx = fmaxf(l0, l1);
        float e0 = expf(l0 - mx), e1 = expf(l1 - mx);
        d_out[2] = e0 / (e0 + e1);
        d_out[3] = e1 / (e0 + e1);
        d_out[4] = (l1 > l0) ? 1.f : 0.f;
    }
}

extern "C" void kernel_launch(void* const* d_in, const int* in_sizes, int n_in,
                              void* d_out, int out_size, void* d_ws, size_t ws_size,
                              hipStream_t stream) {
    const float* h       = (const float*)d_in[0];
    const float* tabular = (const float*)d_in[1];
    const int*   label   = (const int*)d_in[2];
    const float* W_fc    = (const float*)d_in[3];
    const float* b_fc    = (const float*)d_in[4];
    const float* Wa      = (const float*)d_in[5];
    const float* ba      = (const float*)d_in[6];
    const float* Wb      = (const float*)d_in[7];
    const float* bb      = (const float*)d_in[8];
    const float* Wc      = (const float*)d_in[9];
    const float* bc      = (const float*)d_in[10];
    const float* W_inst  = (const float*)d_in[11];
    const float* b_inst  = (const float*)d_in[12];
    const float* W_img   = (const float*)d_in[13];
    const float* b_img   = (const float*)d_in[14];
    const float* W_tab   = (const float*)d_in[15];
    const float* b_tab   = (const float*)d_in[16];
    const float* W_cls   = (const float*)d_in[17];
    const float* b_cls   = (const float*)d_in[18];
    float* out = (float*)d_out;

    // workspace layout (hb last so small-ws fallback works)
    u16* h512 = (u16*)d_ws;                          // NPAD x 512 bf16      (51.2 MB)
    u16* WfcT = h512 + (size_t)NPAD * D1;            // 512 x 1024 bf16      (1 MB)
    u16* WaT  = WfcT + (size_t)D1 * LIN;             // 256 x 512 bf16
    u16* WbT  = WaT + (size_t)D2 * D1;
    u32* uarr = (u32*)(WbT + (size_t)D2 * D1);       // NPAD sortable keys
    float* accum = (float*)(uarr + NPAD);            // [0]=Z, [8..520)=Mpart
    float* Zacc  = accum;
    float* Mpart = accum + 8;
    int* ids = (int*)(accum + 8 + D1);               // 128 selected indices
    int* ctl = ids + 128;                            // 16 ints: buckets+counters
    u32* hist = (u32*)(ctl + 16);                    // 65536 bins
    u32* cV0 = hist + NBIN;
    int* cI0 = (int*)(cV0 + CAND_MAX);
    u32* cV1 = (u32*)(cI0 + CAND_MAX);
    int* cI1 = (int*)(cV1 + CAND_MAX);
    u16* hb  = (u16*)(cI1 + CAND_MAX);               // NPAD x 1024 bf16     (102.5 MB)
    size_t need = ((char*)(hb + (size_t)NPAD * LIN)) - (char*)d_ws;
    bool fast = ws_size >= need;

    // zero accum + ids + ctl + hist in one shot (contiguous)
    size_t zbytes = ((char*)(hist + NBIN)) - (char*)accum;
    hipMemsetAsync(accum, 0, zbytes, stream);
    pack_all<<<dim3(1024), dim3(256), 0, stream>>>(h, W_fc, Wa, Wb,
                                                   fast ? hb : (u16*)nullptr, WfcT, WaT, WbT);
    if (fast) {
        gemm_fc_bf<<<dim3(4, NPAD / 128), dim3(256), 0, stream>>>(hb, WfcT, b_fc, h512);
    } else {
        gemm_fc_f32<<<dim3(2, NPAD / 128), dim3(512), 0, stream>>>(h, WfcT, b_fc, h512);
    }
    gemm_attn<<<dim3(NPAD / 128), dim3(512), 0, stream>>>(
        h512, WaT, WbT, ba, bb, Wc, bc, out + 5, uarr, hist, Zacc, Mpart);
    topk_scan<<<dim3(1), dim3(1024), 0, stream>>>(hist, ctl);
    topk_collect<<<dim3(128), dim3(256), 0, stream>>>(uarr, ctl, ids, cV0, cI0, cV1, cI1);
    topk_finish<<<dim3(1), dim3(256), 0, stream>>>(ctl, cV0, cI0, cV1, cI1, ids);
    inst_loss<<<dim3(1), dim3(256), 0, stream>>>(h512, ids, W_inst, b_inst, label, out + 50005);
    final_head<<<dim3(1), dim3(256), 0, stream>>>(
        Mpart, Zacc, tabular, W_img, b_img, W_tab, b_tab, W_cls, b_cls, out);
}

// Round 4
// 340.552 us; speedup vs baseline: 1.1838x; 1.0215x over previous
//
#include <hip/hip_runtime.h>
#include <stdint.h>

typedef __bf16 bf16x8 __attribute__((ext_vector_type(8)));
typedef float f32x4 __attribute__((ext_vector_type(4)));
typedef unsigned short u16;
typedef unsigned int u32;

#define N_INST 50000
#define NPAD   50048   // 391 * 128
#define LIN    1024
#define D1     512
#define D2     256
#define TOPK   64
#define TDIM   49
#define NBIN   65536
#define CAND_MAX 8192
// dwords to zero: accum(520) + ids(128) + ctl(16) + hist(65536)
#define ZERO_DW (520 + 128 + 16 + NBIN)

__device__ __forceinline__ float b2f(u16 u) {
    union { float f; u32 i; } x; x.i = ((u32)u) << 16; return x.f;
}
__device__ __forceinline__ u16 f2b(float f) {
    union { float f; u32 i; } x; x.f = f;
    u32 r = x.i + 0x7FFFu + ((x.i >> 16) & 1u);   // RNE
    return (u16)(r >> 16);
}
// async global->LDS, 16B per lane. dst must be linear in lane order (wave-uniform base + lane*16).
__device__ __forceinline__ void gload16(const void* g, void* l) {
    __builtin_amdgcn_global_load_lds((const __attribute__((address_space(1))) void*)g,
                                     (__attribute__((address_space(3))) void*)l, 16, 0, 0);
}

// ---------------- pack: h fp32 -> bf16 [NPAD][1024] (zero pad rows); W_fc/Wa/Wb transposed bf16
// Also zeroes the accumulator/histogram region (replaces a pathologically slow rocclr fill).
__global__ void pack_all(const float* __restrict__ h, const float* __restrict__ W_fc,
                         const float* __restrict__ Wa, const float* __restrict__ Wb,
                         u16* __restrict__ hb, u16* __restrict__ WfcT,
                         u16* __restrict__ WaT, u16* __restrict__ WbT,
                         u32* __restrict__ zbase) {
    int gt = blockIdx.x * blockDim.x + threadIdx.x;
    int nthr = gridDim.x * blockDim.x;
    for (int z = gt; z < ZERO_DW; z += nthr) zbase[z] = 0u;
    if (hb) {
        const int HC = NPAD * LIN / 8;          // 8 elems per chunk
        for (int c = gt; c < HC; c += nthr) {
            int row = c >> 7;                   // 128 chunks per row
            uint4 o;
            if (row < N_INST) {
                const float4* p = (const float4*)(h + (size_t)c * 8);
                float4 v0 = p[0], v1 = p[1];
                o.x = (u32)f2b(v0.x) | ((u32)f2b(v0.y) << 16);
                o.y = (u32)f2b(v0.z) | ((u32)f2b(v0.w) << 16);
                o.z = (u32)f2b(v1.x) | ((u32)f2b(v1.y) << 16);
                o.w = (u32)f2b(v1.z) | ((u32)f2b(v1.w) << 16);
            } else {
                o.x = o.y = o.z = o.w = 0u;
            }
            *(uint4*)(hb + (size_t)c * 8) = o;
        }
    }
    for (int e = gt; e < D1 * LIN; e += nthr) {
        int n = e >> 10, k = e & 1023;
        WfcT[e] = f2b(W_fc[(size_t)k * D1 + n]);
    }
    for (int f = gt; f < D2 * D1; f += nthr) {
        int j = f >> 9, k = f & 511;
        WaT[f] = f2b(Wa[(size_t)k * D2 + j]);
        WbT[f] = f2b(Wb[(size_t)k * D2 + j]);
    }
}

// ---------------- GEMM1 (fast path): h512 = relu(hb @ W_fc + b_fc). m97 structure.
__global__ __launch_bounds__(256, 3)
void gemm_fc_bf(const u16* __restrict__ hb, const u16* __restrict__ WfcT,
                const float* __restrict__ b_fc, u16* __restrict__ h512) {
    __shared__ __align__(16) u16 lA[128 * 64];
    __shared__ __align__(16) u16 lB[128 * 64];
    const int tid = threadIdx.x;
    const int lane = tid & 63, wid = tid >> 6;
    const int wr = wid >> 1, wc = wid & 1;
    const int lanelo = lane & 15, lanehi = lane >> 4;
    const int row0 = blockIdx.y * 128;
    const int col0 = blockIdx.x * 128;

    f32x4 acc[4][4];
    const f32x4 z4 = {0.f, 0.f, 0.f, 0.f};
    for (int m = 0; m < 4; ++m)
        for (int n = 0; n < 4; ++n) acc[m][n] = z4;

    for (int kt = 0; kt < LIN / 64; ++kt) {
        #pragma unroll
        for (int q = 0; q < 4; ++q) {
            int c = tid + 256 * q;
            int row = c >> 3, k8 = c & 7;
            gload16(hb + (size_t)(row0 + row) * LIN + kt * 64 + k8 * 8, (char*)lA + c * 16);
        }
        #pragma unroll
        for (int q = 0; q < 4; ++q) {
            int c = tid + 256 * q;
            int col = c >> 3, k8 = c & 7;
            gload16(WfcT + (size_t)(col0 + col) * LIN + kt * 64 + k8 * 8, (char*)lB + c * 16);
        }
        __syncthreads();
        #pragma unroll
        for (int kk = 0; kk < 2; ++kk) {
            bf16x8 af[4], bfr[4];
            #pragma unroll
            for (int m = 0; m < 4; ++m)
                af[m] = *(const bf16x8*)((char*)lA + (wr * 64 + m * 16 + lanelo) * 128 + kk * 64 + lanehi * 16);
            #pragma unroll
            for (int n = 0; n < 4; ++n)
                bfr[n] = *(const bf16x8*)((char*)lB + (wc * 64 + n * 16 + lanelo) * 128 + kk * 64 + lanehi * 16);
            #pragma unroll
            for (int m = 0; m < 4; ++m)
                #pragma unroll
                for (int n = 0; n < 4; ++n)
                    acc[m][n] = __builtin_amdgcn_mfma_f32_16x16x32_bf16(af[m], bfr[n], acc[m][n], 0, 0, 0);
        }
        __syncthreads();
    }
    #pragma unroll
    for (int n = 0; n < 4; ++n) {
        int col = col0 + wc * 64 + n * 16 + lanelo;
        float bias = b_fc[col];
        #pragma unroll
        for (int m = 0; m < 4; ++m) {
            int rbase = row0 + wr * 64 + m * 16 + 4 * lanehi;
            #pragma unroll
            for (int r = 0; r < 4; ++r) {
                float v = acc[m][n][r] + bias;
                v = v > 0.f ? v : 0.f;
                h512[(size_t)(rbase + r) * D1 + col] = f2b(v);
            }
        }
    }
}

// ---------------- GEMM1 (fallback if workspace too small for hb): fp32 A, reg-staged
__global__ __launch_bounds__(512, 2)
void gemm_fc_f32(const float* __restrict__ h, const u16* __restrict__ WfcT,
                 const float* __restrict__ b_fc, u16* __restrict__ h512) {
    __shared__ __align__(16) u16 lA[128 * 64];
    __shared__ __align__(16) u16 lB[256 * 64];
    const int tid = threadIdx.x;
    const int lane = tid & 63, wid = tid >> 6;
    const int wr = wid >> 2, wc = wid & 3;
    const int lanelo = lane & 15, lanehi = lane >> 4;
    const int row0 = blockIdx.y * 128;
    const int col0 = blockIdx.x * 256;

    f32x4 acc[4][4];
    const f32x4 z4 = {0.f, 0.f, 0.f, 0.f};
    for (int m = 0; m < 4; ++m)
        for (int n = 0; n < 4; ++n) acc[m][n] = z4;

    for (int kt = 0; kt < LIN / 64; ++kt) {
        #pragma unroll
        for (int q = 0; q < 4; ++q) {
            int idx = tid + 512 * q;
            int row = idx >> 4, k4 = idx & 15;
            int srow = row0 + row; if (srow >= N_INST) srow = N_INST - 1;
            const float4 v = *(const float4*)(h + (size_t)srow * LIN + kt * 64 + k4 * 4);
            ushort4 b; b.x = f2b(v.x); b.y = f2b(v.y); b.z = f2b(v.z); b.w = f2b(v.w);
            u32 off = row * 128 + ((k4 * 8) ^ ((row & 7) << 4));
            *(ushort4*)((char*)lA + off) = b;
        }
        #pragma unroll
        for (int q = 0; q < 4; ++q) {
            int idx = tid + 512 * q;
            int c = idx >> 3, k8 = idx & 7;
            uint4 v = *(const uint4*)(WfcT + (size_t)(col0 + c) * LIN + kt * 64 + k8 * 8);
            u32 off = c * 128 + ((k8 * 16) ^ ((c & 7) << 4));
            *(uint4*)((char*)lB + off) = v;
        }
        __syncthreads();
        #pragma unroll
        for (int kk = 0; kk < 2; ++kk) {
            bf16x8 af[4], bfr[4];
            #pragma unroll
            for (int m = 0; m < 4; ++m) {
                int row = wr * 64 + m * 16 + lanelo;
                u32 off = row * 128 + (((u32)(kk * 64 + lanehi * 16)) ^ ((row & 7) << 4));
                af[m] = *(const bf16x8*)((char*)lA + off);
            }
            #pragma unroll
            for (int n = 0; n < 4; ++n) {
                int c = wc * 64 + n * 16 + lanelo;
                u32 off = c * 128 + (((u32)(kk * 64 + lanehi * 16)) ^ ((c & 7) << 4));
                bfr[n] = *(const bf16x8*)((char*)lB + off);
            }
            #pragma unroll
            for (int m = 0; m < 4; ++m)
                #pragma unroll
                for (int n = 0; n < 4; ++n)
                    acc[m][n] = __builtin_amdgcn_mfma_f32_16x16x32_bf16(af[m], bfr[n], acc[m][n], 0, 0, 0);
        }
        __syncthreads();
    }
    #pragma unroll
    for (int n = 0; n < 4; ++n) {
        int col = col0 + wc * 64 + n * 16 + lanelo;
        float bias = b_fc[col];
        #pragma unroll
        for (int m = 0; m < 4; ++m) {
            int rbase = row0 + wr * 64 + m * 16 + 4 * lanehi;
            #pragma unroll
            for (int r = 0; r < 4; ++r) {
                float v = acc[m][n][r] + bias;
                v = v > 0.f ? v : 0.f;
                h512[(size_t)(rbase + r) * D1 + col] = f2b(v);
            }
        }
    }
}

// ---------------- GEMM2 fused + sortable keys + 64K-bin key histogram + Z/M partials
__global__ __launch_bounds__(512, 2)
void gemm_attn(const u16* __restrict__ h512, const u16* __restrict__ WaT,
               const u16* __restrict__ WbT, const float* __restrict__ ba,
               const float* __restrict__ bb, const float* __restrict__ Wc,
               const float* __restrict__ bc, float* __restrict__ araw,
               u32* __restrict__ uarr, u32* __restrict__ hist,
               float* __restrict__ Zacc, float* __restrict__ Mpart) {
    __shared__ __align__(16) u16 lA[128 * 64];
    __shared__ __align__(16) u16 lBa[256 * 64];
    __shared__ __align__(16) u16 lBb[256 * 64];
    __shared__ float rsum[128];
    __shared__ float sW[128];
    const int tid = threadIdx.x;
    const int lane = tid & 63, wid = tid >> 6;
    const int wr = wid >> 2, wc4 = wid & 3;
    const int lanelo = lane & 15, lanehi = lane >> 4;
    const int row0 = blockIdx.x * 128;

    f32x4 accA[4][4], accB[4][4];
    const f32x4 z4 = {0.f, 0.f, 0.f, 0.f};
    for (int m = 0; m < 4; ++m)
        for (int n = 0; n < 4; ++n) { accA[m][n] = z4; accB[m][n] = z4; }

    for (int kt = 0; kt < D1 / 64; ++kt) {
        #pragma unroll
        for (int q = 0; q < 2; ++q) {
            int c = tid + 512 * q;
            int row = c >> 3, k8 = c & 7;
            gload16(h512 + (size_t)(row0 + row) * D1 + kt * 64 + k8 * 8, (char*)lA + c * 16);
        }
        #pragma unroll
        for (int q = 0; q < 4; ++q) {
            int c = tid + 512 * q;
            int col = c >> 3, k8 = c & 7;
            gload16(WaT + (size_t)col * D1 + kt * 64 + k8 * 8, (char*)lBa + c * 16);
            gload16(WbT + (size_t)col * D1 + kt * 64 + k8 * 8, (char*)lBb + c * 16);
        }
        __syncthreads();
        #pragma unroll
        for (int kk = 0; kk < 2; ++kk) {
            bf16x8 af[4], ga[4], gb[4];
            #pragma unroll
            for (int m = 0; m < 4; ++m)
                af[m] = *(const bf16x8*)((char*)lA + (wr * 64 + m * 16 + lanelo) * 128 + kk * 64 + lanehi * 16);
            #pragma unroll
            for (int n = 0; n < 4; ++n) {
                u32 off = (wc4 * 64 + n * 16 + lanelo) * 128 + kk * 64 + lanehi * 16;
                ga[n] = *(const bf16x8*)((char*)lBa + off);
                gb[n] = *(const bf16x8*)((char*)lBb + off);
            }
            #pragma unroll
            for (int m = 0; m < 4; ++m)
                #pragma unroll
                for (int n = 0; n < 4; ++n) {
                    accA[m][n] = __builtin_amdgcn_mfma_f32_16x16x32_bf16(af[m], ga[n], accA[m][n], 0, 0, 0);
                    accB[m][n] = __builtin_amdgcn_mfma_f32_16x16x32_bf16(af[m], gb[n], accB[m][n], 0, 0, 0);
                }
        }
        __syncthreads();
    }

    if (tid < 128) rsum[tid] = 0.f;
    __syncthreads();

    float baR[4], bbR[4], wcR[4];
    #pragma unroll
    for (int n = 0; n < 4; ++n) {
        int j = wc4 * 64 + n * 16 + lanelo;
        baR[n] = ba[j]; bbR[n] = bb[j]; wcR[n] = Wc[j];
    }
    #pragma unroll
    for (int m = 0; m < 4; ++m) {
        #pragma unroll
        for (int r = 0; r < 4; ++r) {
            float s = 0.f;
            #pragma unroll
            for (int n = 0; n < 4; ++n) {
                float av = accA[m][n][r] + baR[n];
                float bv = accB[m][n][r] + bbR[n];
                float p = tanhf(av) / (1.f + expf(-bv));
                s += p * wcR[n];
            }
            s += __shfl_xor(s, 1); s += __shfl_xor(s, 2);
            s += __shfl_xor(s, 4); s += __shfl_xor(s, 8);
            if (lanelo == 0) atomicAdd(&rsum[wr * 64 + m * 16 + 4 * lanehi + r], s);
        }
    }
    __syncthreads();

    if (tid < 128) {
        int rg = row0 + tid;
        float e = 0.f;
        if (rg < N_INST) {
            float a = rsum[tid] + bc[0];
            araw[rg] = a;
            u32 bits = __float_as_uint(a);
            u32 key = (bits & 0x80000000u) ? ~bits : (bits | 0x80000000u);
            uarr[rg] = key;
            atomicAdd(&hist[key >> 16], 1u);
            e = expf(a);
        }
        sW[tid] = e;
    }
    __syncthreads();
    if (tid < 128) {
        float e = sW[tid];
        for (int o = 32; o > 0; o >>= 1) e += __shfl_xor(e, o);
        if (lane == 0) atomicAdd(Zacc, e);
    }
    float accM = 0.f;
    for (int i = 0; i < 128; ++i)
        accM += sW[i] * b2f(h512[(size_t)(row0 + i) * D1 + tid]);
    atomicAdd(&Mpart[tid], accM);
}

// ---------------- topk phase 1: scan 64K-bin histogram, find boundary buckets
// ctl: [0]=p0 [1]=base0 [2]=p1 [3]=base1; [8..11] = counters (pre-zeroed)
__global__ void topk_scan(const u32* __restrict__ hist, int* __restrict__ ctl) {
    __shared__ int lds[1024];
    const int tid = threadIdx.x;               // 1024
    const int base = tid * 64;
    int local = 0;
    for (int i = 0; i < 64; ++i) local += (int)hist[base + i];
    lds[tid] = local;
    __syncthreads();
    for (int off = 1; off < 1024; off <<= 1) {
        int v = lds[tid];
        int add = (tid >= off) ? lds[tid - off] : 0;
        __syncthreads();
        lds[tid] = v + add;
        __syncthreads();
    }
    int run = lds[tid] - local;                // exclusive prefix = S(base)
    for (int i = 0; i < 64; ++i) {
        int b = base + i;
        int cnt = (int)hist[b];
        if (cnt > 0) {
            int less = run;
            int greater = N_INST - run - cnt;
            if (greater < TOPK && greater + cnt >= TOPK) { ctl[0] = b; ctl[1] = greater; }
            if (less < TOPK && less + cnt >= TOPK)       { ctl[2] = b; ctl[3] = less; }
        }
        run += cnt;
    }
}

// ---------------- topk phase 2: one pass — directs into ids, boundary-bucket candidates out
__global__ void topk_collect(const u32* __restrict__ uarr, int* __restrict__ ctl,
                             int* __restrict__ ids, u32* __restrict__ cV0, int* __restrict__ cI0,
                             u32* __restrict__ cV1, int* __restrict__ cI1) {
    const int p0 = ctl[0], p1 = ctl[2];
    int gt = blockIdx.x * blockDim.x + threadIdx.x;
    int nthr = gridDim.x * blockDim.x;
    for (int i = gt; i < N_INST; i += nthr) {
        u32 v = uarr[i];
        int b = (int)(v >> 16);
        if (b > p0)       { int p = atomicAdd(&ctl[8], 1);  ids[p] = i; }
        else if (b == p0) { int p = atomicAdd(&ctl[9], 1);  if (p < CAND_MAX) { cV0[p] = v; cI0[p] = i; } }
        if (b < p1)       { int p = atomicAdd(&ctl[10], 1); ids[TOPK + p] = i; }
        else if (b == p1) { int p = atomicAdd(&ctl[11], 1); if (p < CAND_MAX) { cV1[p] = v; cI1[p] = i; } }
    }
}

// ---------------- topk phase 3: finish selection within boundary bucket (tiny)
__global__ void topk_finish(const int* __restrict__ ctl,
                            const u32* __restrict__ cV0, const int* __restrict__ cI0,
                            const u32* __restrict__ cV1, const int* __restrict__ cI1,
                            int* __restrict__ ids) {
    __shared__ int h8[256];
    __shared__ int eq[2048];
    __shared__ int s_d1, s_k1, s_d2, s_fill, s_eqc;
    const int tid = threadIdx.x;               // 256
    for (int mode = 0; mode < 2; ++mode) {
        int basem = ctl[mode * 2 + 1];
        int need = TOPK - basem;
        int ccnt = ctl[9 + mode * 2];
        if (ccnt > CAND_MAX) ccnt = CAND_MAX;
        const u32* cV = mode ? cV1 : cV0;
        const int* cI = mode ? cI1 : cI0;
        int* dst = ids + mode * TOPK;
        // level 1: bits 15:8
        h8[tid] = 0; __syncthreads();
        for (int i = tid; i < ccnt; i += 256) atomicAdd(&h8[(cV[i] >> 8) & 255u], 1);
        __syncthreads();
        if (tid == 0) {
            int acc = 0, d, k = need;
            if (mode == 0) { for (d = 255; d >= 0; --d) { acc += h8[d]; if (acc >= k) break; } }
            else           { for (d = 0; d < 256; ++d)  { acc += h8[d]; if (acc >= k) break; } }
            s_d1 = d; s_k1 = k - (acc - h8[d]);
        }
        __syncthreads();
        int d1 = s_d1, k1 = s_k1;
        // level 2: bits 7:0 among digit-d1 candidates
        h8[tid] = 0; __syncthreads();
        for (int i = tid; i < ccnt; i += 256) {
            u32 v = cV[i];
            if (((v >> 8) & 255u) == (u32)d1) atomicAdd(&h8[v & 255u], 1);
        }
        __syncthreads();
        if (tid == 0) {
            int acc = 0, d, k = k1;
            if (mode == 0) { for (d = 255; d >= 0; --d) { acc += h8[d]; if (acc >= k) break; } }
            else           { for (d = 0; d < 256; ++d)  { acc += h8[d]; if (acc >= k) break; } }
            s_d2 = d; s_fill = 0; s_eqc = 0;
        }
        __syncthreads();
        u32 vth = ((u32)ctl[mode * 2] << 16) | ((u32)d1 << 8) | (u32)s_d2;
        for (int i = tid; i < ccnt; i += 256) {
            u32 v = cV[i];
            bool better = mode == 0 ? (v > vth) : (v < vth);
            if (better)        { int p = atomicAdd(&s_fill, 1); dst[basem + p] = cI[i]; }
            else if (v == vth) { int p = atomicAdd(&s_eqc, 1);  if (p < 2048) eq[p] = cI[i]; }
        }
        __syncthreads();
        if (tid == 0) {
            int have = basem + s_fill;
            int rem = TOPK - have;
            int m = s_eqc < 2048 ? s_eqc : 2048;
            int last = -1;
            for (int t = 0; t < rem; ++t) {
                int best = 0x7FFFFFFF;
                for (int s = 0; s < m; ++s) { int ix = eq[s]; if (ix > last && ix < best) best = ix; }
                dst[have + t] = best; last = best;
            }
        }
        __syncthreads();
    }
}

// ---------------- instance CE loss over gathered 128 rows
__global__ void inst_loss(const u16* __restrict__ h512, const int* __restrict__ ids,
                          const float* __restrict__ W_inst, const float* __restrict__ b_inst,
                          const int* __restrict__ label, float* __restrict__ out_loss) {
    __shared__ float lsum;
    const int tid = threadIdx.x;               // 256
    const int lane = tid & 63, wid = tid >> 6;
    if (tid == 0) lsum = 0.f;
    __syncthreads();
    const int lab = label[0];
    const float* W = W_inst + (size_t)lab * (D1 * 2);
    const float b0 = b_inst[lab * 2 + 0], b1 = b_inst[lab * 2 + 1];
    for (int i = 0; i < 32; ++i) {
        int r = wid * 32 + i;
        int row = ids[r];
        float s0 = 0.f, s1 = 0.f;
        for (int s = 0; s < 8; ++s) {
            int j = lane + 64 * s;
            float hv = b2f(h512[(size_t)row * D1 + j]);
            s0 += hv * W[j * 2 + 0];
            s1 += hv * W[j * 2 + 1];
        }
        for (int o = 32; o > 0; o >>= 1) { s0 += __shfl_xor(s0, o); s1 += __shfl_xor(s1, o); }
        if (lane == 0) {
            float l0 = s0 + b0, l1 = s1 + b1;
            float mx = fmaxf(l0, l1);
            float lse = mx + logf(expf(l0 - mx) + expf(l1 - mx));
            float lt = (r < TOPK) ? l1 : l0;
            atomicAdd(&lsum, lse - lt);
        }
    }
    __syncthreads();
    if (tid == 0) out_loss[0] = lsum / 128.f;
}

// ---------------- final head
__global__ void final_head(const float* __restrict__ Mpart, const float* __restrict__ Zacc,
                           const float* __restrict__ tabular, const float* __restrict__ W_img,
                           const float* __restrict__ b_img, const float* __restrict__ W_tab,
                           const float* __restrict__ b_tab, const float* __restrict__ W_cls,
                           const float* __restrict__ b_cls, float* __restrict__ d_out) {
    __shared__ float sM[512];
    __shared__ float stab[TDIM];
    __shared__ float red0[256], red1[256];
    __shared__ float simg;
    const int tid = threadIdx.x;               // 256
    float invZ = 1.f / Zacc[0];
    sM[tid] = Mpart[tid] * invZ;
    sM[tid + 256] = Mpart[tid + 256] * invZ;
    red0[tid] = sM[tid] * W_img[tid] + sM[tid + 256] * W_img[tid + 256];
    __syncthreads();
    for (int o = 128; o > 0; o >>= 1) { if (tid < o) red0[tid] += red0[tid + o]; __syncthreads(); }
    if (tid == 0) simg = 1.f / (1.f + expf(-(red0[0] + b_img[0])));
    if (tid < TDIM) {
        float t = b_tab[tid];
        for (int kx = 0; kx < TDIM; ++kx) t += tabular[kx] * W_tab[kx * TDIM + tid];
        stab[tid] = t;
    }
    __syncthreads();
    if (tid == 0) {
        float mx = stab[0];
        for (int o = 1; o < TDIM; ++o) mx = fmaxf(mx, stab[o]);
        float ss = 0.f;
        for (int o = 0; o < TDIM; ++o) { float e = expf(stab[o] - mx); stab[o] = e; ss += e; }
        for (int o = 0; o < TDIM; ++o) stab[o] = (stab[o] / ss) * tabular[o];
    }
    __syncthreads();
    float img = simg;
    float a0 = 0.f, a1 = 0.f;
    for (int j = tid; j < D1 + TDIM; j += 256) {
        float w = (j < D1) ? img * sM[j] : stab[j - D1];
        a0 += w * W_cls[j * 2 + 0];
        a1 += w * W_cls[j * 2 + 1];
    }
    red0[tid] = a0; red1[tid] = a1;
    __syncthreads();
    for (int o = 128; o > 0; o >>= 1) {
        if (tid < o) { red0[tid] += red0[tid + o]; red1[tid] += red1[tid + o]; }
        __syncthreads();
    }
    if (tid == 0) {
        float l0 = red0[0] + b_cls[0];
        float l1 = red1[0] + b_cls[1];
        d_out[0] = l0; d_out[1] = l1;
        float mx = fmaxf(l0, l1);
        float e0 = expf(l0 - mx), e1 = expf(l1 - mx);
        d_out[2] = e0 / (e0 + e1);
        d_out[3] = e1 / (e0 + e1);
        d_out[4] = (l1 > l0) ? 1.f : 0.f;
    }
}

extern "C" void kernel_launch(void* const* d_in, const int* in_sizes, int n_in,
                              void* d_out, int out_size, void* d_ws, size_t ws_size,
                              hipStream_t stream) {
    const float* h       = (const float*)d_in[0];
    const float* tabular = (const float*)d_in[1];
    const int*   label   = (const int*)d_in[2];
    const float* W_fc    = (const float*)d_in[3];
    const float* b_fc    = (const float*)d_in[4];
    const float* Wa      = (const float*)d_in[5];
    const float* ba      = (const float*)d_in[6];
    const float* Wb      = (const float*)d_in[7];
    const float* bb      = (const float*)d_in[8];
    const float* Wc      = (const float*)d_in[9];
    const float* bc      = (const float*)d_in[10];
    const float* W_inst  = (const float*)d_in[11];
    const float* b_inst  = (const float*)d_in[12];
    const float* W_img   = (const float*)d_in[13];
    const float* b_img   = (const float*)d_in[14];
    const float* W_tab   = (const float*)d_in[15];
    const float* b_tab   = (const float*)d_in[16];
    const float* W_cls   = (const float*)d_in[17];
    const float* b_cls   = (const float*)d_in[18];
    float* out = (float*)d_out;

    // workspace layout (hb last so small-ws fallback works)
    u16* h512 = (u16*)d_ws;                          // NPAD x 512 bf16      (51.2 MB)
    u16* WfcT = h512 + (size_t)NPAD * D1;            // 512 x 1024 bf16      (1 MB)
    u16* WaT  = WfcT + (size_t)D1 * LIN;             // 256 x 512 bf16
    u16* WbT  = WaT + (size_t)D2 * D1;
    u32* uarr = (u32*)(WbT + (size_t)D2 * D1);       // NPAD sortable keys
    float* accum = (float*)(uarr + NPAD);            // [0]=Z, [8..520)=Mpart
    float* Zacc  = accum;
    float* Mpart = accum + 8;
    int* ids = (int*)(accum + 8 + D1);               // 128 selected indices
    int* ctl = ids + 128;                            // 16 ints: buckets+counters
    u32* hist = (u32*)(ctl + 16);                    // 65536 bins
    u32* cV0 = hist + NBIN;
    int* cI0 = (int*)(cV0 + CAND_MAX);
    u32* cV1 = (u32*)(cI0 + CAND_MAX);
    int* cI1 = (int*)(cV1 + CAND_MAX);
    u16* hb  = (u16*)(cI1 + CAND_MAX);               // NPAD x 1024 bf16     (102.5 MB)
    size_t need = ((char*)(hb + (size_t)NPAD * LIN)) - (char*)d_ws;
    bool fast = ws_size >= need;

    // pack_all also zeroes accum..hist (ZERO_DW dwords starting at accum) —
    // replaces hipMemsetAsync whose rocclr fill kernel cost ~118 us.
    pack_all<<<dim3(1024), dim3(256), 0, stream>>>(h, W_fc, Wa, Wb,
                                                   fast ? hb : (u16*)nullptr, WfcT, WaT, WbT,
                                                   (u32*)accum);
    if (fast) {
        gemm_fc_bf<<<dim3(4, NPAD / 128), dim3(256), 0, stream>>>(hb, WfcT, b_fc, h512);
    } else {
        gemm_fc_f32<<<dim3(2, NPAD / 128), dim3(512), 0, stream>>>(h, WfcT, b_fc, h512);
    }
    gemm_attn<<<dim3(NPAD / 128), dim3(512), 0, stream>>>(
        h512, WaT, WbT, ba, bb, Wc, bc, out + 5, uarr, hist, Zacc, Mpart);
    topk_scan<<<dim3(1), dim3(1024), 0, stream>>>(hist, ctl);
    topk_collect<<<dim3(128), dim3(256), 0, stream>>>(uarr, ctl, ids, cV0, cI0, cV1, cI1);
    topk_finish<<<dim3(1), dim3(256), 0, stream>>>(ctl, cV0, cI0, cV1, cI1, ids);
    inst_loss<<<dim3(1), dim3(256), 0, stream>>>(h512, ids, W_inst, b_inst, label, out + 50005);
    final_head<<<dim3(1), dim3(256), 0, stream>>>(
        Mpart, Zacc, tabular, W_img, b_img, W_tab, b_tab, W_cls, b_cls, out);
}

// Round 5
// 319.492 us; speedup vs baseline: 1.2618x; 1.0659x over previous
//
#include <hip/hip_runtime.h>
#include <stdint.h>

typedef __bf16 bf16x8 __attribute__((ext_vector_type(8)));
typedef float f32x4 __attribute__((ext_vector_type(4)));
typedef unsigned short u16;
typedef unsigned int u32;

#define N_INST 50000
#define NPAD   50048   // 391 * 128
#define LIN    1024
#define D1     512
#define D2     256
#define TOPK   64
#define TDIM   49
#define NBIN   65536
#define CAND_MAX 8192
// dwords to zero: accum(520) + ids(128) + ctl(16) + hist(65536)
#define ZERO_DW (520 + 128 + 16 + NBIN)

__device__ __forceinline__ float b2f(u16 u) {
    union { float f; u32 i; } x; x.i = ((u32)u) << 16; return x.f;
}
__device__ __forceinline__ u16 f2b(float f) {
    union { float f; u32 i; } x; x.f = f;
    u32 r = x.i + 0x7FFFu + ((x.i >> 16) & 1u);   // RNE
    return (u16)(r >> 16);
}
// async global->LDS, 16B per lane. dst must be linear in lane order (wave-uniform base + lane*16).
__device__ __forceinline__ void gload16(const void* g, void* l) {
    __builtin_amdgcn_global_load_lds((const __attribute__((address_space(1))) void*)g,
                                     (__attribute__((address_space(3))) void*)l, 16, 0, 0);
}

// ---------------- pack weights (tiny): W_fc -> WfcT bf16 [512][1024]; Wa/Wb -> [256][512]
// Also zeroes the accumulator/histogram region (replaces pathologically slow rocclr fill).
__global__ void pack_w(const float* __restrict__ W_fc, const float* __restrict__ Wa,
                       const float* __restrict__ Wb, u16* __restrict__ WfcT,
                       u16* __restrict__ WaT, u16* __restrict__ WbT, u32* __restrict__ zbase) {
    int gt = blockIdx.x * blockDim.x + threadIdx.x;
    int nthr = gridDim.x * blockDim.x;
    for (int z = gt; z < ZERO_DW; z += nthr) zbase[z] = 0u;
    for (int e = gt; e < D1 * LIN; e += nthr) {
        int n = e >> 10, k = e & 1023;
        WfcT[e] = f2b(W_fc[(size_t)k * D1 + n]);
    }
    for (int f = gt; f < D2 * D1; f += nthr) {
        int j = f >> 9, k = f & 511;
        WaT[f] = f2b(Wa[(size_t)k * D2 + j]);
        WbT[f] = f2b(Wb[(size_t)k * D2 + j]);
    }
}

// ---------------- GEMM1 fused convert: h512 = relu(h_fp32 @ W_fc + b_fc), h read ONCE.
// BM=128, BN=512 (full width), BK=64. 8 waves 2x4, wave tile 64x128 (acc 4x8).
// A: reg-staged fp32 -> bf16 (native cvt) -> LDS. B: global_load_lds width-16.
__global__ __launch_bounds__(512, 2)
void gemm_fc(const float* __restrict__ h, const u16* __restrict__ WfcT,
             const float* __restrict__ b_fc, u16* __restrict__ h512) {
    __shared__ __align__(16) u16 lA[128 * 64];    // 16 KB
    __shared__ __align__(16) u16 lB[512 * 64];    // 64 KB
    const int tid = threadIdx.x;
    const int lane = tid & 63, wid = tid >> 6;
    const int wr = wid >> 2, wc = wid & 3;        // 2 x 4 wave grid
    const int lanelo = lane & 15, lanehi = lane >> 4;
    const int row0 = blockIdx.x * 128;

    const int arow = tid >> 2;                    // 0..127
    const int aseg = tid & 3;                     // 16 floats each
    int srow = row0 + arow; if (srow >= N_INST) srow = N_INST - 1;
    const float* abase = h + (size_t)srow * LIN + aseg * 16;

    f32x4 acc[4][8];
    const f32x4 z4 = {0.f, 0.f, 0.f, 0.f};
    #pragma unroll
    for (int m = 0; m < 4; ++m)
        #pragma unroll
        for (int n = 0; n < 8; ++n) acc[m][n] = z4;

    for (int kt = 0; kt < LIN / 64; ++kt) {
        // B: 512x64 bf16 = 64KB = 4096 chunks, async direct-to-LDS (issue first)
        #pragma unroll
        for (int q = 0; q < 8; ++q) {
            int c = tid + 512 * q;
            int col = c >> 3, k8 = c & 7;
            gload16(WfcT + (size_t)col * LIN + kt * 64 + k8 * 8, (char*)lB + c * 16);
        }
        // A: 128x64 fp32, reg-stage + convert + ds_write (overlaps B latency)
        {
            const float4* ap = (const float4*)(abase + kt * 64);
            float4 a0 = ap[0], a1 = ap[1], a2 = ap[2], a3 = ap[3];
            bf16x8 w0, w1;
            w0[0] = (__bf16)a0.x; w0[1] = (__bf16)a0.y; w0[2] = (__bf16)a0.z; w0[3] = (__bf16)a0.w;
            w0[4] = (__bf16)a1.x; w0[5] = (__bf16)a1.y; w0[6] = (__bf16)a1.z; w0[7] = (__bf16)a1.w;
            w1[0] = (__bf16)a2.x; w1[1] = (__bf16)a2.y; w1[2] = (__bf16)a2.z; w1[3] = (__bf16)a2.w;
            w1[4] = (__bf16)a3.x; w1[5] = (__bf16)a3.y; w1[6] = (__bf16)a3.z; w1[7] = (__bf16)a3.w;
            *(bf16x8*)(lA + arow * 64 + aseg * 16) = w0;
            *(bf16x8*)(lA + arow * 64 + aseg * 16 + 8) = w1;
        }
        __syncthreads();
        #pragma unroll
        for (int kk = 0; kk < 2; ++kk) {
            bf16x8 af[4], bfr[8];
            #pragma unroll
            for (int m = 0; m < 4; ++m)
                af[m] = *(const bf16x8*)((char*)lA + (wr * 64 + m * 16 + lanelo) * 128 + kk * 64 + lanehi * 16);
            #pragma unroll
            for (int n = 0; n < 8; ++n)
                bfr[n] = *(const bf16x8*)((char*)lB + (wc * 128 + n * 16 + lanelo) * 128 + kk * 64 + lanehi * 16);
            #pragma unroll
            for (int m = 0; m < 4; ++m)
                #pragma unroll
                for (int n = 0; n < 8; ++n)
                    acc[m][n] = __builtin_amdgcn_mfma_f32_16x16x32_bf16(af[m], bfr[n], acc[m][n], 0, 0, 0);
        }
        __syncthreads();
    }
    // epilogue: bias + relu -> bf16
    #pragma unroll
    for (int n = 0; n < 8; ++n) {
        int col = wc * 128 + n * 16 + lanelo;
        float bias = b_fc[col];
        #pragma unroll
        for (int m = 0; m < 4; ++m) {
            int rbase = row0 + wr * 64 + m * 16 + 4 * lanehi;
            #pragma unroll
            for (int r = 0; r < 4; ++r) {
                float v = acc[m][n][r] + bias;
                v = v > 0.f ? v : 0.f;
                h512[(size_t)(rbase + r) * D1 + col] = f2b(v);
            }
        }
    }
}

// ---------------- GEMM2 fused + sortable keys + 64K-bin key histogram + Z/M partials
__global__ __launch_bounds__(512, 2)
void gemm_attn(const u16* __restrict__ h512, const u16* __restrict__ WaT,
               const u16* __restrict__ WbT, const float* __restrict__ ba,
               const float* __restrict__ bb, const float* __restrict__ Wc,
               const float* __restrict__ bc, float* __restrict__ araw,
               u32* __restrict__ uarr, u32* __restrict__ hist,
               float* __restrict__ Zacc, float* __restrict__ Mpart) {
    __shared__ __align__(16) u16 lA[128 * 64];
    __shared__ __align__(16) u16 lBa[256 * 64];
    __shared__ __align__(16) u16 lBb[256 * 64];
    __shared__ float rsum[128];
    __shared__ float sW[128];
    const int tid = threadIdx.x;
    const int lane = tid & 63, wid = tid >> 6;
    const int wr = wid >> 2, wc4 = wid & 3;
    const int lanelo = lane & 15, lanehi = lane >> 4;
    const int row0 = blockIdx.x * 128;

    f32x4 accA[4][4], accB[4][4];
    const f32x4 z4 = {0.f, 0.f, 0.f, 0.f};
    for (int m = 0; m < 4; ++m)
        for (int n = 0; n < 4; ++n) { accA[m][n] = z4; accB[m][n] = z4; }

    for (int kt = 0; kt < D1 / 64; ++kt) {
        #pragma unroll
        for (int q = 0; q < 2; ++q) {
            int c = tid + 512 * q;
            int row = c >> 3, k8 = c & 7;
            gload16(h512 + (size_t)(row0 + row) * D1 + kt * 64 + k8 * 8, (char*)lA + c * 16);
        }
        #pragma unroll
        for (int q = 0; q < 4; ++q) {
            int c = tid + 512 * q;
            int col = c >> 3, k8 = c & 7;
            gload16(WaT + (size_t)col * D1 + kt * 64 + k8 * 8, (char*)lBa + c * 16);
            gload16(WbT + (size_t)col * D1 + kt * 64 + k8 * 8, (char*)lBb + c * 16);
        }
        __syncthreads();
        #pragma unroll
        for (int kk = 0; kk < 2; ++kk) {
            bf16x8 af[4], ga[4], gb[4];
            #pragma unroll
            for (int m = 0; m < 4; ++m)
                af[m] = *(const bf16x8*)((char*)lA + (wr * 64 + m * 16 + lanelo) * 128 + kk * 64 + lanehi * 16);
            #pragma unroll
            for (int n = 0; n < 4; ++n) {
                u32 off = (wc4 * 64 + n * 16 + lanelo) * 128 + kk * 64 + lanehi * 16;
                ga[n] = *(const bf16x8*)((char*)lBa + off);
                gb[n] = *(const bf16x8*)((char*)lBb + off);
            }
            #pragma unroll
            for (int m = 0; m < 4; ++m)
                #pragma unroll
                for (int n = 0; n < 4; ++n) {
                    accA[m][n] = __builtin_amdgcn_mfma_f32_16x16x32_bf16(af[m], ga[n], accA[m][n], 0, 0, 0);
                    accB[m][n] = __builtin_amdgcn_mfma_f32_16x16x32_bf16(af[m], gb[n], accB[m][n], 0, 0, 0);
                }
        }
        __syncthreads();
    }

    if (tid < 128) rsum[tid] = 0.f;
    __syncthreads();

    float baR[4], bbR[4], wcR[4];
    #pragma unroll
    for (int n = 0; n < 4; ++n) {
        int j = wc4 * 64 + n * 16 + lanelo;
        baR[n] = ba[j]; bbR[n] = bb[j]; wcR[n] = Wc[j];
    }
    #pragma unroll
    for (int m = 0; m < 4; ++m) {
        #pragma unroll
        for (int r = 0; r < 4; ++r) {
            float s = 0.f;
            #pragma unroll
            for (int n = 0; n < 4; ++n) {
                float av = accA[m][n][r] + baR[n];
                float bv = accB[m][n][r] + bbR[n];
                float p = tanhf(av) / (1.f + expf(-bv));
                s += p * wcR[n];
            }
            s += __shfl_xor(s, 1); s += __shfl_xor(s, 2);
            s += __shfl_xor(s, 4); s += __shfl_xor(s, 8);
            if (lanelo == 0) atomicAdd(&rsum[wr * 64 + m * 16 + 4 * lanehi + r], s);
        }
    }
    __syncthreads();

    if (tid < 128) {
        int rg = row0 + tid;
        float e = 0.f;
        if (rg < N_INST) {
            float a = rsum[tid] + bc[0];
            araw[rg] = a;
            u32 bits = __float_as_uint(a);
            u32 key = (bits & 0x80000000u) ? ~bits : (bits | 0x80000000u);
            uarr[rg] = key;
            atomicAdd(&hist[key >> 16], 1u);
            e = expf(a);
        }
        sW[tid] = e;
    }
    __syncthreads();
    if (tid < 128) {
        float e = sW[tid];
        for (int o = 32; o > 0; o >>= 1) e += __shfl_xor(e, o);
        if (lane == 0) atomicAdd(Zacc, e);
    }
    float accM = 0.f;
    for (int i = 0; i < 128; ++i)
        accM += sW[i] * b2f(h512[(size_t)(row0 + i) * D1 + tid]);
    atomicAdd(&Mpart[tid], accM);
}

// ---------------- topk collect with inline hist scan (every block computes boundaries)
// ctl: [0]=p0 [1]=base0 [2]=p1 [3]=base1; [8..11] = atomic counters (pre-zeroed)
__global__ void topk_collect(const u32* __restrict__ hist, const u32* __restrict__ uarr,
                             int* __restrict__ ctl, int* __restrict__ ids,
                             u32* __restrict__ cV0, int* __restrict__ cI0,
                             u32* __restrict__ cV1, int* __restrict__ cI1) {
    __shared__ int part[256];
    __shared__ int sp0, sb0, sp1, sb1;
    const int t = threadIdx.x;                 // 256
    const uint4* h4 = (const uint4*)hist;
    int s = 0;
    for (int j = 0; j < 64; ++j) {             // bins [t*256, t*256+256)
        uint4 v = h4[t * 64 + j];
        s += (int)(v.x + v.y + v.z + v.w);
    }
    part[t] = s;
    __syncthreads();
    for (int off = 1; off < 256; off <<= 1) {  // inclusive scan
        int v = part[t];
        int a = (t >= off) ? part[t - off] : 0;
        __syncthreads();
        part[t] = v + a;
        __syncthreads();
    }
    int run = part[t] - s;                     // exclusive prefix
    for (int j = 0; j < 64; ++j) {             // walk own chunk (L1-hot)
        uint4 v = h4[t * 64 + j];
        int c4[4]; c4[0] = (int)v.x; c4[1] = (int)v.y; c4[2] = (int)v.z; c4[3] = (int)v.w;
        #pragma unroll
        for (int e = 0; e < 4; ++e) {
            int cnt = c4[e];
            if (cnt > 0) {
                int b = t * 256 + j * 4 + e;
                int less = run, greater = N_INST - run - cnt;
                if (greater < TOPK && greater + cnt >= TOPK) { sp0 = b; sb0 = greater; }
                if (less < TOPK && less + cnt >= TOPK)       { sp1 = b; sb1 = less; }
            }
            run += cnt;
        }
    }
    __syncthreads();
    const int p0 = sp0, p1 = sp1;
    if (blockIdx.x == 0 && t == 0) { ctl[0] = sp0; ctl[1] = sb0; ctl[2] = sp1; ctl[3] = sb1; }

    int gt = blockIdx.x * blockDim.x + t;
    int nthr = gridDim.x * blockDim.x;
    for (int i = gt; i < N_INST; i += nthr) {
        u32 v = uarr[i];
        int b = (int)(v >> 16);
        if (b > p0)       { int p = atomicAdd(&ctl[8], 1);  ids[p] = i; }
        else if (b == p0) { int p = atomicAdd(&ctl[9], 1);  if (p < CAND_MAX) { cV0[p] = v; cI0[p] = i; } }
        if (b < p1)       { int p = atomicAdd(&ctl[10], 1); ids[TOPK + p] = i; }
        else if (b == p1) { int p = atomicAdd(&ctl[11], 1); if (p < CAND_MAX) { cV1[p] = v; cI1[p] = i; } }
    }
}

// ---------------- tail: topk finish + instance CE loss + final head (one block, 256 thr)
__global__ void tail_fused(const int* __restrict__ ctl,
                           const u32* __restrict__ cV0, const int* __restrict__ cI0,
                           const u32* __restrict__ cV1, const int* __restrict__ cI1,
                           int* __restrict__ ids, const u16* __restrict__ h512,
                           const float* __restrict__ W_inst, const float* __restrict__ b_inst,
                           const int* __restrict__ label, const float* __restrict__ Mpart,
                           const float* __restrict__ Zacc, const float* __restrict__ tabular,
                           const float* __restrict__ W_img, const float* __restrict__ b_img,
                           const float* __restrict__ W_tab, const float* __restrict__ b_tab,
                           const float* __restrict__ W_cls, const float* __restrict__ b_cls,
                           float* __restrict__ d_out) {
    __shared__ int h8[256];
    __shared__ int eq[2048];
    __shared__ int s_d1, s_k1, s_d2, s_fill, s_eqc;
    __shared__ float lsum;
    __shared__ float sM[512];
    __shared__ float stab[TDIM];
    __shared__ float red0[256], red1[256];
    __shared__ float simg;
    const int tid = threadIdx.x;               // 256
    const int lane = tid & 63, wid = tid >> 6;

    // ---- phase 1: finish top-k within boundary buckets
    for (int mode = 0; mode < 2; ++mode) {
        int basem = ctl[mode * 2 + 1];
        int need = TOPK - basem;
        int ccnt = ctl[9 + mode * 2];
        if (ccnt > CAND_MAX) ccnt = CAND_MAX;
        const u32* cV = mode ? cV1 : cV0;
        const int* cI = mode ? cI1 : cI0;
        int* dst = ids + mode * TOPK;
        h8[tid] = 0; __syncthreads();
        for (int i = tid; i < ccnt; i += 256) atomicAdd(&h8[(cV[i] >> 8) & 255u], 1);
        __syncthreads();
        if (tid == 0) {
            int acc = 0, d, k = need;
            if (mode == 0) { for (d = 255; d >= 0; --d) { acc += h8[d]; if (acc >= k) break; } }
            else           { for (d = 0; d < 256; ++d)  { acc += h8[d]; if (acc >= k) break; } }
            s_d1 = d; s_k1 = k - (acc - h8[d]);
        }
        __syncthreads();
        int d1 = s_d1, k1 = s_k1;
        h8[tid] = 0; __syncthreads();
        for (int i = tid; i < ccnt; i += 256) {
            u32 v = cV[i];
            if (((v >> 8) & 255u) == (u32)d1) atomicAdd(&h8[v & 255u], 1);
        }
        __syncthreads();
        if (tid == 0) {
            int acc = 0, d, k = k1;
            if (mode == 0) { for (d = 255; d >= 0; --d) { acc += h8[d]; if (acc >= k) break; } }
            else           { for (d = 0; d < 256; ++d)  { acc += h8[d]; if (acc >= k) break; } }
            s_d2 = d; s_fill = 0; s_eqc = 0;
        }
        __syncthreads();
        u32 vth = ((u32)ctl[mode * 2] << 16) | ((u32)d1 << 8) | (u32)s_d2;
        for (int i = tid; i < ccnt; i += 256) {
            u32 v = cV[i];
            bool better = mode == 0 ? (v > vth) : (v < vth);
            if (better)        { int p = atomicAdd(&s_fill, 1); dst[basem + p] = cI[i]; }
            else if (v == vth) { int p = atomicAdd(&s_eqc, 1);  if (p < 2048) eq[p] = cI[i]; }
        }
        __syncthreads();
        if (tid == 0) {
            int have = basem + s_fill;
            int rem = TOPK - have;
            int m = s_eqc < 2048 ? s_eqc : 2048;
            int last = -1;
            for (int q = 0; q < rem; ++q) {
                int best = 0x7FFFFFFF;
                for (int s = 0; s < m; ++s) { int ix = eq[s]; if (ix > last && ix < best) best = ix; }
                dst[have + q] = best; last = best;
            }
        }
        __syncthreads();
    }

    // ---- phase 2: instance CE loss over gathered 128 rows
    if (tid == 0) lsum = 0.f;
    __syncthreads();
    const int lab = label[0];
    const float* W = W_inst + (size_t)lab * (D1 * 2);
    const float b0 = b_inst[lab * 2 + 0], b1 = b_inst[lab * 2 + 1];
    for (int i = 0; i < 32; ++i) {
        int r = wid * 32 + i;
        int row = ids[r];
        float s0 = 0.f, s1 = 0.f;
        for (int s = 0; s < 8; ++s) {
            int j = lane + 64 * s;
            float hv = b2f(h512[(size_t)row * D1 + j]);
            s0 += hv * W[j * 2 + 0];
            s1 += hv * W[j * 2 + 1];
        }
        for (int o = 32; o > 0; o >>= 1) { s0 += __shfl_xor(s0, o); s1 += __shfl_xor(s1, o); }
        if (lane == 0) {
            float l0 = s0 + b0, l1 = s1 + b1;
            float mx = fmaxf(l0, l1);
            float lse = mx + logf(expf(l0 - mx) + expf(l1 - mx));
            float lt = (r < TOPK) ? l1 : l0;
            atomicAdd(&lsum, lse - lt);
        }
    }
    __syncthreads();
    if (tid == 0) d_out[50005] = lsum / 128.f;

    // ---- phase 3: final head
    float invZ = 1.f / Zacc[0];
    sM[tid] = Mpart[tid] * invZ;
    sM[tid + 256] = Mpart[tid + 256] * invZ;
    red0[tid] = sM[tid] * W_img[tid] + sM[tid + 256] * W_img[tid + 256];
    __syncthreads();
    for (int o = 128; o > 0; o >>= 1) { if (tid < o) red0[tid] += red0[tid + o]; __syncthreads(); }
    if (tid == 0) simg = 1.f / (1.f + expf(-(red0[0] + b_img[0])));
    if (tid < TDIM) {
        float t = b_tab[tid];
        for (int kx = 0; kx < TDIM; ++kx) t += tabular[kx] * W_tab[kx * TDIM + tid];
        stab[tid] = t;
    }
    __syncthreads();
    if (tid == 0) {
        float mx = stab[0];
        for (int o = 1; o < TDIM; ++o) mx = fmaxf(mx, stab[o]);
        float ss = 0.f;
        for (int o = 0; o < TDIM; ++o) { float e = expf(stab[o] - mx); stab[o] = e; ss += e; }
        for (int o = 0; o < TDIM; ++o) stab[o] = (stab[o] / ss) * tabular[o];
    }
    __syncthreads();
    float img = simg;
    float a0 = 0.f, a1 = 0.f;
    for (int j = tid; j < D1 + TDIM; j += 256) {
        float w = (j < D1) ? img * sM[j] : stab[j - D1];
        a0 += w * W_cls[j * 2 + 0];
        a1 += w * W_cls[j * 2 + 1];
    }
    red0[tid] = a0; red1[tid] = a1;
    __syncthreads();
    for (int o = 128; o > 0; o >>= 1) {
        if (tid < o) { red0[tid] += red0[tid + o]; red1[tid] += red1[tid + o]; }
        __syncthreads();
    }
    if (tid == 0) {
        float l0 = red0[0] + b_cls[0];
        float l1 = red1[0] + b_cls[1];
        d_out[0] = l0; d_out[1] = l1;
        float mx = fmaxf(l0, l1);
        float e0 = expf(l0 - mx), e1 = expf(l1 - mx);
        d_out[2] = e0 / (e0 + e1);
        d_out[3] = e1 / (e0 + e1);
        d_out[4] = (l1 > l0) ? 1.f : 0.f;
    }
}

extern "C" void kernel_launch(void* const* d_in, const int* in_sizes, int n_in,
                              void* d_out, int out_size, void* d_ws, size_t ws_size,
                              hipStream_t stream) {
    const float* h       = (const float*)d_in[0];
    const float* tabular = (const float*)d_in[1];
    const int*   label   = (const int*)d_in[2];
    const float* W_fc    = (const float*)d_in[3];
    const float* b_fc    = (const float*)d_in[4];
    const float* Wa      = (const float*)d_in[5];
    const float* ba      = (const float*)d_in[6];
    const float* Wb      = (const float*)d_in[7];
    const float* bb      = (const float*)d_in[8];
    const float* Wc      = (const float*)d_in[9];
    const float* bc      = (const float*)d_in[10];
    const float* W_inst  = (const float*)d_in[11];
    const float* b_inst  = (const float*)d_in[12];
    const float* W_img   = (const float*)d_in[13];
    const float* b_img   = (const float*)d_in[14];
    const float* W_tab   = (const float*)d_in[15];
    const float* b_tab   = (const float*)d_in[16];
    const float* W_cls   = (const float*)d_in[17];
    const float* b_cls   = (const float*)d_in[18];
    float* out = (float*)d_out;

    // workspace layout (~53 MB)
    u16* h512 = (u16*)d_ws;                          // NPAD x 512 bf16      (51.2 MB)
    u16* WfcT = h512 + (size_t)NPAD * D1;            // 512 x 1024 bf16      (1 MB)
    u16* WaT  = WfcT + (size_t)D1 * LIN;             // 256 x 512 bf16
    u16* WbT  = WaT + (size_t)D2 * D1;
    u32* uarr = (u32*)(WbT + (size_t)D2 * D1);       // NPAD sortable keys
    float* accum = (float*)(uarr + NPAD);            // [0]=Z, [8..520)=Mpart
    float* Zacc  = accum;
    float* Mpart = accum + 8;
    int* ids = (int*)(accum + 8 + D1);               // 128 selected indices
    int* ctl = ids + 128;                            // 16 ints: buckets+counters
    u32* hist = (u32*)(ctl + 16);                    // 65536 bins
    u32* cV0 = hist + NBIN;
    int* cI0 = (int*)(cV0 + CAND_MAX);
    u32* cV1 = (u32*)(cI0 + CAND_MAX);
    int* cI1 = (int*)(cV1 + CAND_MAX);

    pack_w<<<dim3(256), dim3(256), 0, stream>>>(W_fc, Wa, Wb, WfcT, WaT, WbT, (u32*)accum);
    gemm_fc<<<dim3(NPAD / 128), dim3(512), 0, stream>>>(h, WfcT, b_fc, h512);
    gemm_attn<<<dim3(NPAD / 128), dim3(512), 0, stream>>>(
        h512, WaT, WbT, ba, bb, Wc, bc, out + 5, uarr, hist, Zacc, Mpart);
    topk_collect<<<dim3(128), dim3(256), 0, stream>>>(hist, uarr, ctl, ids, cV0, cI0, cV1, cI1);
    tail_fused<<<dim3(1), dim3(256), 0, stream>>>(
        ctl, cV0, cI0, cV1, cI1, ids, h512, W_inst, b_inst, label,
        Mpart, Zacc, tabular, W_img, b_img, W_tab, b_tab, W_cls, b_cls, out);
}

// Round 6
// 308.679 us; speedup vs baseline: 1.3060x; 1.0350x over previous
//
#include <hip/hip_runtime.h>
#include <stdint.h>

typedef __bf16 bf16x8 __attribute__((ext_vector_type(8)));
typedef float f32x4 __attribute__((ext_vector_type(4)));
typedef unsigned short u16;
typedef unsigned int u32;

#define N_INST 50000
#define NPAD   50048   // 391 * 128
#define LIN    1024
#define D1     512
#define D2     256
#define TOPK   64
#define TDIM   49
#define NBIN   65536
#define CAND_MAX 8192
// dwords to zero: accum(520) + ids(128) + ctl(16) + hist(65536)
#define ZERO_DW (520 + 128 + 16 + NBIN)

__device__ __forceinline__ float b2f(u16 u) {
    union { float f; u32 i; } x; x.i = ((u32)u) << 16; return x.f;
}
__device__ __forceinline__ u16 f2b(float f) {
    union { float f; u32 i; } x; x.f = f;
    u32 r = x.i + 0x7FFFu + ((x.i >> 16) & 1u);   // RNE
    return (u16)(r >> 16);
}
// async global->LDS, 16B per lane. dst must be linear in lane order (wave-uniform base + lane*16).
__device__ __forceinline__ void gload16(const void* g, void* l) {
    __builtin_amdgcn_global_load_lds((const __attribute__((address_space(1))) void*)g,
                                     (__attribute__((address_space(3))) void*)l, 16, 0, 0);
}
// byte offset of a swizzled [row][64 bf16] tile element (T2 st-style XOR swizzle)
__device__ __forceinline__ u32 swz(int row, int bytecol) {
    return (u32)(row * 128 + (bytecol ^ ((row & 7) << 4)));
}

// ---------------- pack weights (tiny): W_fc -> WfcT bf16 [512][1024]; Wa/Wb -> [256][512]
// Also zeroes the accumulator/histogram region (replaces pathologically slow rocclr fill).
__global__ void pack_w(const float* __restrict__ W_fc, const float* __restrict__ Wa,
                       const float* __restrict__ Wb, u16* __restrict__ WfcT,
                       u16* __restrict__ WaT, u16* __restrict__ WbT, u32* __restrict__ zbase) {
    int gt = blockIdx.x * blockDim.x + threadIdx.x;
    int nthr = gridDim.x * blockDim.x;
    for (int z = gt; z < ZERO_DW; z += nthr) zbase[z] = 0u;
    for (int e = gt; e < D1 * LIN; e += nthr) {
        int n = e >> 10, k = e & 1023;
        WfcT[e] = f2b(W_fc[(size_t)k * D1 + n]);
    }
    for (int f = gt; f < D2 * D1; f += nthr) {
        int j = f >> 9, k = f & 511;
        WaT[f] = f2b(Wa[(size_t)k * D2 + j]);
        WbT[f] = f2b(Wb[(size_t)k * D2 + j]);
    }
}

// ---------------- GEMM1 fused convert: h512 = relu(h_fp32 @ W_fc + b_fc).
// BM=128, BN=256, BK=64, 8 waves 2x4 (wave tile 64x64). LDS 48 KB.
// A: fp32 reg-prefetch (issued under previous MFMA) -> bf16 cvt -> swizzled ds_write.
// B: global_load_lds w/ pre-swizzled source. All LDS reads XOR-swizzled (T2).
__global__ __launch_bounds__(512, 2)
void gemm_fc(const float* __restrict__ h, const u16* __restrict__ WfcT,
             const float* __restrict__ b_fc, u16* __restrict__ h512) {
    __shared__ __align__(16) u16 lA[128 * 64];    // 16 KB
    __shared__ __align__(16) u16 lB[256 * 64];    // 32 KB
    const int tid = threadIdx.x;
    const int lane = tid & 63, wid = tid >> 6;
    const int wr = wid >> 2, wc = wid & 3;        // 2 x 4 wave grid, 64x64 each
    const int lanelo = lane & 15, lanehi = lane >> 4;
    const int row0 = blockIdx.y * 128;
    const int col0 = blockIdx.x * 256;

    const int arow = tid >> 2;                    // 0..127
    const int aseg = tid & 3;                     // 16 floats each
    int srow = row0 + arow; if (srow >= N_INST) srow = N_INST - 1;
    const float* abase = h + (size_t)srow * LIN + aseg * 16;
    u16* aw0 = (u16*)((char*)lA + swz(arow, aseg * 32));
    u16* aw1 = (u16*)((char*)lA + swz(arow, aseg * 32 + 16));

    f32x4 acc[4][4];
    const f32x4 z4 = {0.f, 0.f, 0.f, 0.f};
    #pragma unroll
    for (int m = 0; m < 4; ++m)
        #pragma unroll
        for (int n = 0; n < 4; ++n) acc[m][n] = z4;

    float4 a0, a1, a2, a3;
    { const float4* ap = (const float4*)abase; a0 = ap[0]; a1 = ap[1]; a2 = ap[2]; a3 = ap[3]; }

    for (int kt = 0; kt < LIN / 64; ++kt) {
        // B: 256x64 bf16 = 2048 chunks, async direct-to-LDS, source pre-swizzled
        #pragma unroll
        for (int q = 0; q < 4; ++q) {
            int c = tid + 512 * q;
            int col = c >> 3, d8 = c & 7;
            int k8 = d8 ^ (col & 7);
            gload16(WfcT + (size_t)(col0 + col) * LIN + kt * 64 + k8 * 8, (char*)lB + c * 16);
        }
        // A: convert prefetched fp32 regs -> bf16, swizzled ds_write
        {
            bf16x8 w0, w1;
            w0[0] = (__bf16)a0.x; w0[1] = (__bf16)a0.y; w0[2] = (__bf16)a0.z; w0[3] = (__bf16)a0.w;
            w0[4] = (__bf16)a1.x; w0[5] = (__bf16)a1.y; w0[6] = (__bf16)a1.z; w0[7] = (__bf16)a1.w;
            w1[0] = (__bf16)a2.x; w1[1] = (__bf16)a2.y; w1[2] = (__bf16)a2.z; w1[3] = (__bf16)a2.w;
            w1[4] = (__bf16)a3.x; w1[5] = (__bf16)a3.y; w1[6] = (__bf16)a3.z; w1[7] = (__bf16)a3.w;
            *(bf16x8*)aw0 = w0;
            *(bf16x8*)aw1 = w1;
        }
        __syncthreads();
        // prefetch next A tile (latency hides under MFMA below; drained at 2nd barrier)
        if (kt + 1 < LIN / 64) {
            const float4* ap = (const float4*)(abase + (kt + 1) * 64);
            a0 = ap[0]; a1 = ap[1]; a2 = ap[2]; a3 = ap[3];
        }
        #pragma unroll
        for (int kk = 0; kk < 2; ++kk) {
            bf16x8 af[4], bfr[4];
            #pragma unroll
            for (int m = 0; m < 4; ++m) {
                int row = wr * 64 + m * 16 + lanelo;
                af[m] = *(const bf16x8*)((char*)lA + swz(row, kk * 64 + lanehi * 16));
            }
            #pragma unroll
            for (int n = 0; n < 4; ++n) {
                int col = wc * 64 + n * 16 + lanelo;
                bfr[n] = *(const bf16x8*)((char*)lB + swz(col, kk * 64 + lanehi * 16));
            }
            #pragma unroll
            for (int m = 0; m < 4; ++m)
                #pragma unroll
                for (int n = 0; n < 4; ++n)
                    acc[m][n] = __builtin_amdgcn_mfma_f32_16x16x32_bf16(af[m], bfr[n], acc[m][n], 0, 0, 0);
        }
        __syncthreads();
    }
    // epilogue: bias + relu -> bf16
    #pragma unroll
    for (int n = 0; n < 4; ++n) {
        int col = col0 + wc * 64 + n * 16 + lanelo;
        float bias = b_fc[col];
        #pragma unroll
        for (int m = 0; m < 4; ++m) {
            int rbase = row0 + wr * 64 + m * 16 + 4 * lanehi;
            #pragma unroll
            for (int r = 0; r < 4; ++r) {
                float v = acc[m][n][r] + bias;
                v = v > 0.f ? v : 0.f;
                h512[(size_t)(rbase + r) * D1 + col] = f2b(v);
            }
        }
    }
}

// ---------------- GEMM2 fused + sortable keys + 64K-bin key histogram + Z/M partials
// All three LDS tiles use pre-swizzled gload sources + swizzled reads (T2).
__global__ __launch_bounds__(512, 2)
void gemm_attn(const u16* __restrict__ h512, const u16* __restrict__ WaT,
               const u16* __restrict__ WbT, const float* __restrict__ ba,
               const float* __restrict__ bb, const float* __restrict__ Wc,
               const float* __restrict__ bc, float* __restrict__ araw,
               u32* __restrict__ uarr, u32* __restrict__ hist,
               float* __restrict__ Zacc, float* __restrict__ Mpart) {
    __shared__ __align__(16) u16 lA[128 * 64];
    __shared__ __align__(16) u16 lBa[256 * 64];
    __shared__ __align__(16) u16 lBb[256 * 64];
    __shared__ float rsum[128];
    __shared__ float sW[128];
    const int tid = threadIdx.x;
    const int lane = tid & 63, wid = tid >> 6;
    const int wr = wid >> 2, wc4 = wid & 3;
    const int lanelo = lane & 15, lanehi = lane >> 4;
    const int row0 = blockIdx.x * 128;

    f32x4 accA[4][4], accB[4][4];
    const f32x4 z4 = {0.f, 0.f, 0.f, 0.f};
    for (int m = 0; m < 4; ++m)
        for (int n = 0; n < 4; ++n) { accA[m][n] = z4; accB[m][n] = z4; }

    for (int kt = 0; kt < D1 / 64; ++kt) {
        #pragma unroll
        for (int q = 0; q < 2; ++q) {
            int c = tid + 512 * q;
            int row = c >> 3, d8 = c & 7;
            int k8 = d8 ^ (row & 7);
            gload16(h512 + (size_t)(row0 + row) * D1 + kt * 64 + k8 * 8, (char*)lA + c * 16);
        }
        #pragma unroll
        for (int q = 0; q < 4; ++q) {
            int c = tid + 512 * q;
            int col = c >> 3, d8 = c & 7;
            int k8 = d8 ^ (col & 7);
            gload16(WaT + (size_t)col * D1 + kt * 64 + k8 * 8, (char*)lBa + c * 16);
            gload16(WbT + (size_t)col * D1 + kt * 64 + k8 * 8, (char*)lBb + c * 16);
        }
        __syncthreads();
        #pragma unroll
        for (int kk = 0; kk < 2; ++kk) {
            bf16x8 af[4], ga[4], gb[4];
            #pragma unroll
            for (int m = 0; m < 4; ++m) {
                int row = wr * 64 + m * 16 + lanelo;
                af[m] = *(const bf16x8*)((char*)lA + swz(row, kk * 64 + lanehi * 16));
            }
            #pragma unroll
            for (int n = 0; n < 4; ++n) {
                int col = wc4 * 64 + n * 16 + lanelo;
                u32 off = swz(col, kk * 64 + lanehi * 16);
                ga[n] = *(const bf16x8*)((char*)lBa + off);
                gb[n] = *(const bf16x8*)((char*)lBb + off);
            }
            #pragma unroll
            for (int m = 0; m < 4; ++m)
                #pragma unroll
                for (int n = 0; n < 4; ++n) {
                    accA[m][n] = __builtin_amdgcn_mfma_f32_16x16x32_bf16(af[m], ga[n], accA[m][n], 0, 0, 0);
                    accB[m][n] = __builtin_amdgcn_mfma_f32_16x16x32_bf16(af[m], gb[n], accB[m][n], 0, 0, 0);
                }
        }
        __syncthreads();
    }

    if (tid < 128) rsum[tid] = 0.f;
    __syncthreads();

    float baR[4], bbR[4], wcR[4];
    #pragma unroll
    for (int n = 0; n < 4; ++n) {
        int j = wc4 * 64 + n * 16 + lanelo;
        baR[n] = ba[j]; bbR[n] = bb[j]; wcR[n] = Wc[j];
    }
    #pragma unroll
    for (int m = 0; m < 4; ++m) {
        #pragma unroll
        for (int r = 0; r < 4; ++r) {
            float s = 0.f;
            #pragma unroll
            for (int n = 0; n < 4; ++n) {
                float av = accA[m][n][r] + baR[n];
                float bv = accB[m][n][r] + bbR[n];
                float p = tanhf(av) / (1.f + expf(-bv));
                s += p * wcR[n];
            }
            s += __shfl_xor(s, 1); s += __shfl_xor(s, 2);
            s += __shfl_xor(s, 4); s += __shfl_xor(s, 8);
            if (lanelo == 0) atomicAdd(&rsum[wr * 64 + m * 16 + 4 * lanehi + r], s);
        }
    }
    __syncthreads();

    if (tid < 128) {
        int rg = row0 + tid;
        float e = 0.f;
        if (rg < N_INST) {
            float a = rsum[tid] + bc[0];
            araw[rg] = a;
            u32 bits = __float_as_uint(a);
            u32 key = (bits & 0x80000000u) ? ~bits : (bits | 0x80000000u);
            uarr[rg] = key;
            atomicAdd(&hist[key >> 16], 1u);
            e = expf(a);
        }
        sW[tid] = e;
    }
    __syncthreads();
    if (tid < 128) {
        float e = sW[tid];
        for (int o = 32; o > 0; o >>= 1) e += __shfl_xor(e, o);
        if (lane == 0) atomicAdd(Zacc, e);
    }
    float accM = 0.f;
    for (int i = 0; i < 128; ++i)
        accM += sW[i] * b2f(h512[(size_t)(row0 + i) * D1 + tid]);
    atomicAdd(&Mpart[tid], accM);
}

// ---------------- topk collect with inline hist scan (every block computes boundaries)
// ctl: [0]=p0 [1]=base0 [2]=p1 [3]=base1; [8..11] = atomic counters (pre-zeroed)
__global__ void topk_collect(const u32* __restrict__ hist, const u32* __restrict__ uarr,
                             int* __restrict__ ctl, int* __restrict__ ids,
                             u32* __restrict__ cV0, int* __restrict__ cI0,
                             u32* __restrict__ cV1, int* __restrict__ cI1) {
    __shared__ int part[256];
    __shared__ int sp0, sb0, sp1, sb1;
    const int t = threadIdx.x;                 // 256
    const uint4* h4 = (const uint4*)hist;
    int s = 0;
    for (int j = 0; j < 64; ++j) {             // bins [t*256, t*256+256)
        uint4 v = h4[t * 64 + j];
        s += (int)(v.x + v.y + v.z + v.w);
    }
    part[t] = s;
    __syncthreads();
    for (int off = 1; off < 256; off <<= 1) {  // inclusive scan
        int v = part[t];
        int a = (t >= off) ? part[t - off] : 0;
        __syncthreads();
        part[t] = v + a;
        __syncthreads();
    }
    int run = part[t] - s;                     // exclusive prefix
    for (int j = 0; j < 64; ++j) {             // walk own chunk (L1-hot)
        uint4 v = h4[t * 64 + j];
        int c4[4]; c4[0] = (int)v.x; c4[1] = (int)v.y; c4[2] = (int)v.z; c4[3] = (int)v.w;
        #pragma unroll
        for (int e = 0; e < 4; ++e) {
            int cnt = c4[e];
            if (cnt > 0) {
                int b = t * 256 + j * 4 + e;
                int less = run, greater = N_INST - run - cnt;
                if (greater < TOPK && greater + cnt >= TOPK) { sp0 = b; sb0 = greater; }
                if (less < TOPK && less + cnt >= TOPK)       { sp1 = b; sb1 = less; }
            }
            run += cnt;
        }
    }
    __syncthreads();
    const int p0 = sp0, p1 = sp1;
    if (blockIdx.x == 0 && t == 0) { ctl[0] = sp0; ctl[1] = sb0; ctl[2] = sp1; ctl[3] = sb1; }

    int gt = blockIdx.x * blockDim.x + t;
    int nthr = gridDim.x * blockDim.x;
    for (int i = gt; i < N_INST; i += nthr) {
        u32 v = uarr[i];
        int b = (int)(v >> 16);
        if (b > p0)       { int p = atomicAdd(&ctl[8], 1);  ids[p] = i; }
        else if (b == p0) { int p = atomicAdd(&ctl[9], 1);  if (p < CAND_MAX) { cV0[p] = v; cI0[p] = i; } }
        if (b < p1)       { int p = atomicAdd(&ctl[10], 1); ids[TOPK + p] = i; }
        else if (b == p1) { int p = atomicAdd(&ctl[11], 1); if (p < CAND_MAX) { cV1[p] = v; cI1[p] = i; } }
    }
}

// ---------------- tail: topk finish + instance CE loss + final head (one block, 256 thr)
__global__ void tail_fused(const int* __restrict__ ctl,
                           const u32* __restrict__ cV0, const int* __restrict__ cI0,
                           const u32* __restrict__ cV1, const int* __restrict__ cI1,
                           int* __restrict__ ids, const u16* __restrict__ h512,
                           const float* __restrict__ W_inst, const float* __restrict__ b_inst,
                           const int* __restrict__ label, const float* __restrict__ Mpart,
                           const float* __restrict__ Zacc, const float* __restrict__ tabular,
                           const float* __restrict__ W_img, const float* __restrict__ b_img,
                           const float* __restrict__ W_tab, const float* __restrict__ b_tab,
                           const float* __restrict__ W_cls, const float* __restrict__ b_cls,
                           float* __restrict__ d_out) {
    __shared__ int h8[256];
    __shared__ int eq[2048];
    __shared__ int s_d1, s_k1, s_d2, s_fill, s_eqc;
    __shared__ float lsum;
    __shared__ float sM[512];
    __shared__ float stab[TDIM];
    __shared__ float red0[256], red1[256];
    __shared__ float simg;
    const int tid = threadIdx.x;               // 256
    const int lane = tid & 63, wid = tid >> 6;

    // ---- phase 1: finish top-k within boundary buckets
    for (int mode = 0; mode < 2; ++mode) {
        int basem = ctl[mode * 2 + 1];
        int need = TOPK - basem;
        int ccnt = ctl[9 + mode * 2];
        if (ccnt > CAND_MAX) ccnt = CAND_MAX;
        const u32* cV = mode ? cV1 : cV0;
        const int* cI = mode ? cI1 : cI0;
        int* dst = ids + mode * TOPK;
        h8[tid] = 0; __syncthreads();
        for (int i = tid; i < ccnt; i += 256) atomicAdd(&h8[(cV[i] >> 8) & 255u], 1);
        __syncthreads();
        if (tid == 0) {
            int acc = 0, d, k = need;
            if (mode == 0) { for (d = 255; d >= 0; --d) { acc += h8[d]; if (acc >= k) break; } }
            else           { for (d = 0; d < 256; ++d)  { acc += h8[d]; if (acc >= k) break; } }
            s_d1 = d; s_k1 = k - (acc - h8[d]);
        }
        __syncthreads();
        int d1 = s_d1, k1 = s_k1;
        h8[tid] = 0; __syncthreads();
        for (int i = tid; i < ccnt; i += 256) {
            u32 v = cV[i];
            if (((v >> 8) & 255u) == (u32)d1) atomicAdd(&h8[v & 255u], 1);
        }
        __syncthreads();
        if (tid == 0) {
            int acc = 0, d, k = k1;
            if (mode == 0) { for (d = 255; d >= 0; --d) { acc += h8[d]; if (acc >= k) break; } }
            else           { for (d = 0; d < 256; ++d)  { acc += h8[d]; if (acc >= k) break; } }
            s_d2 = d; s_fill = 0; s_eqc = 0;
        }
        __syncthreads();
        u32 vth = ((u32)ctl[mode * 2] << 16) | ((u32)d1 << 8) | (u32)s_d2;
        for (int i = tid; i < ccnt; i += 256) {
            u32 v = cV[i];
            bool better = mode == 0 ? (v > vth) : (v < vth);
            if (better)        { int p = atomicAdd(&s_fill, 1); dst[basem + p] = cI[i]; }
            else if (v == vth) { int p = atomicAdd(&s_eqc, 1);  if (p < 2048) eq[p] = cI[i]; }
        }
        __syncthreads();
        if (tid == 0) {
            int have = basem + s_fill;
            int rem = TOPK - have;
            int m = s_eqc < 2048 ? s_eqc : 2048;
            int last = -1;
            for (int q = 0; q < rem; ++q) {
                int best = 0x7FFFFFFF;
                for (int s = 0; s < m; ++s) { int ix = eq[s]; if (ix > last && ix < best) best = ix; }
                dst[have + q] = best; last = best;
            }
        }
        __syncthreads();
    }

    // ---- phase 2: instance CE loss over gathered 128 rows
    if (tid == 0) lsum = 0.f;
    __syncthreads();
    const int lab = label[0];
    const float* W = W_inst + (size_t)lab * (D1 * 2);
    const float b0 = b_inst[lab * 2 + 0], b1 = b_inst[lab * 2 + 1];
    for (int i = 0; i < 32; ++i) {
        int r = wid * 32 + i;
        int row = ids[r];
        float s0 = 0.f, s1 = 0.f;
        for (int s = 0; s < 8; ++s) {
            int j = lane + 64 * s;
            float hv = b2f(h512[(size_t)row * D1 + j]);
            s0 += hv * W[j * 2 + 0];
            s1 += hv * W[j * 2 + 1];
        }
        for (int o = 32; o > 0; o >>= 1) { s0 += __shfl_xor(s0, o); s1 += __shfl_xor(s1, o); }
        if (lane == 0) {
            float l0 = s0 + b0, l1 = s1 + b1;
            float mx = fmaxf(l0, l1);
            float lse = mx + logf(expf(l0 - mx) + expf(l1 - mx));
            float lt = (r < TOPK) ? l1 : l0;
            atomicAdd(&lsum, lse - lt);
        }
    }
    __syncthreads();
    if (tid == 0) d_out[50005] = lsum / 128.f;

    // ---- phase 3: final head
    float invZ = 1.f / Zacc[0];
    sM[tid] = Mpart[tid] * invZ;
    sM[tid + 256] = Mpart[tid + 256] * invZ;
    red0[tid] = sM[tid] * W_img[tid] + sM[tid + 256] * W_img[tid + 256];
    __syncthreads();
    for (int o = 128; o > 0; o >>= 1) { if (tid < o) red0[tid] += red0[tid + o]; __syncthreads(); }
    if (tid == 0) simg = 1.f / (1.f + expf(-(red0[0] + b_img[0])));
    if (tid < TDIM) {
        float t = b_tab[tid];
        for (int kx = 0; kx < TDIM; ++kx) t += tabular[kx] * W_tab[kx * TDIM + tid];
        stab[tid] = t;
    }
    __syncthreads();
    if (tid == 0) {
        float mx = stab[0];
        for (int o = 1; o < TDIM; ++o) mx = fmaxf(mx, stab[o]);
        float ss = 0.f;
        for (int o = 0; o < TDIM; ++o) { float e = expf(stab[o] - mx); stab[o] = e; ss += e; }
        for (int o = 0; o < TDIM; ++o) stab[o] = (stab[o] / ss) * tabular[o];
    }
    __syncthreads();
    float img = simg;
    float a0 = 0.f, a1 = 0.f;
    for (int j = tid; j < D1 + TDIM; j += 256) {
        float w = (j < D1) ? img * sM[j] : stab[j - D1];
        a0 += w * W_cls[j * 2 + 0];
        a1 += w * W_cls[j * 2 + 1];
    }
    red0[tid] = a0; red1[tid] = a1;
    __syncthreads();
    for (int o = 128; o > 0; o >>= 1) {
        if (tid < o) { red0[tid] += red0[tid + o]; red1[tid] += red1[tid + o]; }
        __syncthreads();
    }
    if (tid == 0) {
        float l0 = red0[0] + b_cls[0];
        float l1 = red1[0] + b_cls[1];
        d_out[0] = l0; d_out[1] = l1;
        float mx = fmaxf(l0, l1);
        float e0 = expf(l0 - mx), e1 = expf(l1 - mx);
        d_out[2] = e0 / (e0 + e1);
        d_out[3] = e1 / (e0 + e1);
        d_out[4] = (l1 > l0) ? 1.f : 0.f;
    }
}

extern "C" void kernel_launch(void* const* d_in, const int* in_sizes, int n_in,
                              void* d_out, int out_size, void* d_ws, size_t ws_size,
                              hipStream_t stream) {
    const float* h       = (const float*)d_in[0];
    const float* tabular = (const float*)d_in[1];
    const int*   label   = (const int*)d_in[2];
    const float* W_fc    = (const float*)d_in[3];
    const float* b_fc    = (const float*)d_in[4];
    const float* Wa      = (const float*)d_in[5];
    const float* ba      = (const float*)d_in[6];
    const float* Wb      = (const float*)d_in[7];
    const float* bb      = (const float*)d_in[8];
    const float* Wc      = (const float*)d_in[9];
    const float* bc      = (const float*)d_in[10];
    const float* W_inst  = (const float*)d_in[11];
    const float* b_inst  = (const float*)d_in[12];
    const float* W_img   = (const float*)d_in[13];
    const float* b_img   = (const float*)d_in[14];
    const float* W_tab   = (const float*)d_in[15];
    const float* b_tab   = (const float*)d_in[16];
    const float* W_cls   = (const float*)d_in[17];
    const float* b_cls   = (const float*)d_in[18];
    float* out = (float*)d_out;

    // workspace layout (~53 MB)
    u16* h512 = (u16*)d_ws;                          // NPAD x 512 bf16      (51.2 MB)
    u16* WfcT = h512 + (size_t)NPAD * D1;            // 512 x 1024 bf16      (1 MB)
    u16* WaT  = WfcT + (size_t)D1 * LIN;             // 256 x 512 bf16
    u16* WbT  = WaT + (size_t)D2 * D1;
    u32* uarr = (u32*)(WbT + (size_t)D2 * D1);       // NPAD sortable keys
    float* accum = (float*)(uarr + NPAD);            // [0]=Z, [8..520)=Mpart
    float* Zacc  = accum;
    float* Mpart = accum + 8;
    int* ids = (int*)(accum + 8 + D1);               // 128 selected indices
    int* ctl = ids + 128;                            // 16 ints: buckets+counters
    u32* hist = (u32*)(ctl + 16);                    // 65536 bins
    u32* cV0 = hist + NBIN;
    int* cI0 = (int*)(cV0 + CAND_MAX);
    u32* cV1 = (u32*)(cI0 + CAND_MAX);
    int* cI1 = (int*)(cV1 + CAND_MAX);

    pack_w<<<dim3(256), dim3(256), 0, stream>>>(W_fc, Wa, Wb, WfcT, WaT, WbT, (u32*)accum);
    gemm_fc<<<dim3(2, NPAD / 128), dim3(512), 0, stream>>>(h, WfcT, b_fc, h512);
    gemm_attn<<<dim3(NPAD / 128), dim3(512), 0, stream>>>(
        h512, WaT, WbT, ba, bb, Wc, bc, out + 5, uarr, hist, Zacc, Mpart);
    topk_collect<<<dim3(128), dim3(256), 0, stream>>>(hist, uarr, ctl, ids, cV0, cI0, cV1, cI1);
    tail_fused<<<dim3(1), dim3(256), 0, stream>>>(
        ctl, cV0, cI0, cV1, cI1, ids, h512, W_inst, b_inst, label,
        Mpart, Zacc, tabular, W_img, b_img, W_tab, b_tab, W_cls, b_cls, out);
}